// Round 1
// baseline (1182.954 us; speedup 1.0000x reference)
//
#include <hip/hip_runtime.h>

// GraphGRU on MI355X. Pipeline:
//   prep: transpose+bf16-cast weights (W^T, S^T per role), gate vectors g=sigmoid(Wg+bg)
//   CSR:  histogram(col) -> single-block scan -> scatter sorted src ids; role-sort nodes
//   pass1: gemm_xt (5 convs, MFMA bf16) -> agg5 (wave/node register accumulate) ->
//          gemm_self (role-sorted, += into aggr) -> combine1 (z, q=r*h, txh)
//   pass2: gemm_xt(hh on q) -> agg1 -> gemm_self(hh) -> combine2 (h_new)
// ws usage ~264 MB (5x fp32 aggr, 5x bf16 xt, 5x bf16 m, CSR arrays, weights).

typedef __bf16 bf16;
typedef __bf16 bf16x2 __attribute__((ext_vector_type(2)));
typedef __bf16 bf16x4 __attribute__((ext_vector_type(4)));
typedef __bf16 bf16x8 __attribute__((ext_vector_type(8)));
typedef float  f32x4  __attribute__((ext_vector_type(4)));

#define DH 128

__device__ __forceinline__ float sigmoidf_(float x) { return 1.0f / (1.0f + expf(-x)); }
__device__ __forceinline__ float reluf_(float x) { return fmaxf(x, 0.0f); }

// ---------------- weight prep ----------------
struct WPtrs { const float* W[6]; const float* S[6]; };

// dst: 24 matrices [n][k] bf16 (transposed): 0..5 = W_c, 6..23 = S_c[r] (mat=6+c*3+r)
__global__ __launch_bounds__(256) void transpose_cast_kernel(WPtrs wp, bf16* __restrict__ dst)
{
  int b = blockIdx.x;                       // 24*64 blocks
  int mat = b >> 6;
  int idx = (b & 63) * 256 + threadIdx.x;   // 0..16383 over [k][n]
  const float* src = (mat < 6) ? wp.W[mat]
                               : (wp.S[(mat - 6) / 3] + (size_t)((mat - 6) % 3) * (DH * DH));
  int k = idx >> 7, n = idx & 127;
  dst[(size_t)mat * (DH * DH) + n * DH + k] = (bf16)src[idx];
}

struct GateP { const float* Wg[6]; const float* bg[6]; };

__global__ __launch_bounds__(256) void gates_kernel(GateP gp, float* __restrict__ g)
{
  int i = blockIdx.x * 256 + threadIdx.x;   // 6*3*128 = 2304
  if (i < 2304) {
    int c = i / 384, j = i - c * 384;
    g[i] = sigmoidf_(gp.Wg[c][j] + gp.bg[c][j]);
  }
}

// ---------------- CSR build (counting sort by col) ----------------
__global__ __launch_bounds__(256) void hist_kernel(const int* __restrict__ ei, int* __restrict__ cnt,
                                                   int E, int N)
{
  int i = blockIdx.x * 256 + threadIdx.x;
  if (i < E + N) {
    int c = (i < E) ? ei[E + i] : (i - E);  // self loops appended
    atomicAdd(&cnt[c], 1);
  }
}

__global__ __launch_bounds__(1024) void scan_kernel(const int* __restrict__ cnt, int* __restrict__ off, int n)
{
  __shared__ int wsum[17];                  // [16] = running carry
  int t = threadIdx.x, lane = t & 63, w = t >> 6;
  if (t == 0) { wsum[16] = 0; off[0] = 0; }
  __syncthreads();
  for (int base = 0; base < n; base += 1024) {
    int carry = wsum[16];
    int idx = base + t;
    int v = (idx < n) ? cnt[idx] : 0;
    int s = v;
    #pragma unroll
    for (int d = 1; d < 64; d <<= 1) { int u = __shfl_up(s, d); if (lane >= d) s += u; }
    if (lane == 63) wsum[w] = s;
    __syncthreads();
    if (w == 0 && lane < 16) {
      int ws = wsum[lane];
      #pragma unroll
      for (int d = 1; d < 16; d <<= 1) { int u = __shfl_up(ws, d); if (lane >= d) ws += u; }
      wsum[lane] = ws;
    }
    __syncthreads();
    int inc = carry + ((w > 0) ? wsum[w - 1] : 0) + s;
    if (idx < n) off[idx + 1] = inc;
    __syncthreads();
    if (t == 0) wsum[16] = carry + wsum[15];
    __syncthreads();
  }
}

__global__ __launch_bounds__(256) void scatter_kernel(const int* __restrict__ ei, int* __restrict__ fill,
                                                      int* __restrict__ ssrc, int E, int N)
{
  int i = blockIdx.x * 256 + threadIdx.x;
  if (i < E + N) {
    int c, r;
    if (i < E) { c = ei[E + i]; r = ei[i]; } else { c = i - E; r = i - E; }
    int pz = atomicAdd(&fill[c], 1);
    ssrc[pz] = r;
  }
}

// ---------------- role sort of nodes ----------------
__global__ __launch_bounds__(256) void rolehist_kernel(const int* __restrict__ role, int* __restrict__ rolecnt, int N)
{
  int i = blockIdx.x * 256 + threadIdx.x;
  int lane = threadIdx.x & 63;
  int r = (i < N) ? role[i] : -1;
  #pragma unroll
  for (int rr = 0; rr < 3; ++rr) {
    unsigned long long mask = __ballot(r == rr);
    if (lane == 0 && mask) atomicAdd(&rolecnt[rr], __popcll(mask));
  }
}

__global__ void roleoff_kernel(const int* __restrict__ rolecnt, int* __restrict__ rolefill)
{
  rolefill[0] = 0;
  rolefill[1] = rolecnt[0];
  rolefill[2] = rolecnt[0] + rolecnt[1];
}

__global__ __launch_bounds__(256) void permscatter_kernel(const int* __restrict__ role, int* __restrict__ rolefill,
                                                          int* __restrict__ perm, int* __restrict__ rsort, int N)
{
  int i = blockIdx.x * 256 + threadIdx.x;
  int lane = threadIdx.x & 63;
  int r = (i < N) ? role[i] : -1;
  #pragma unroll
  for (int rr = 0; rr < 3; ++rr) {
    unsigned long long mask = __ballot(r == rr);
    if (!mask) continue;
    int base = 0;
    if (lane == 0) base = atomicAdd(&rolefill[rr], __popcll(mask));
    base = __shfl(base, 0);
    if (r == rr) {
      int rank = (int)__popcll(mask & ((1ull << lane) - 1ull));
      perm[base + rank] = i;
      rsort[base + rank] = rr;
    }
  }
}

// ---------------- MFMA GEMMs ----------------
// Tile: 64 rows x 128 cols, K=128 in one shot. 4 waves, wave w owns rows [w*16,w*16+16).
// A frag: m=lane&15, k=(lane>>4)*8+j ; B frag from W^T LDS rows ; C/D: col=lane&15, row=quad*4+reg.

struct XtArgs {
  const float* A[5];
  const bf16*  Bt[5];
  const float* g[5];
  const float* bias[5];
  bf16* Xt[5];
  bf16* Mo[5];
};

__global__ __launch_bounds__(256) void gemm_xt_kernel(XtArgs args, const int* __restrict__ role, int Mrows)
{
  const int cv = blockIdx.y;
  const float* __restrict__ A    = args.A[cv];
  const bf16*  __restrict__ Bt   = args.Bt[cv];
  const float* __restrict__ gv   = args.g[cv];
  const float* __restrict__ bias = args.bias[cv];
  bf16* __restrict__ Xt = args.Xt[cv];
  bf16* __restrict__ Mo = args.Mo[cv];

  __shared__ alignas(16) bf16 As[64][136];   // +8 pad: 2-way LDS aliasing only (free)
  __shared__ alignas(16) bf16 Bs[128][136];

  const int tid = threadIdx.x;
  const int row0 = blockIdx.x * 64;

  #pragma unroll
  for (int it = 0; it < 8; ++it) {           // A: 64x128 fp32 -> bf16 LDS
    int i = it * 256 + tid;
    int r = i >> 5, c4 = (i & 31) << 2;
    int t = row0 + r;
    float4 v = make_float4(0.f, 0.f, 0.f, 0.f);
    if (t < Mrows) v = *(const float4*)(A + (size_t)t * DH + c4);
    bf16x4 o; o[0] = (bf16)v.x; o[1] = (bf16)v.y; o[2] = (bf16)v.z; o[3] = (bf16)v.w;
    *(bf16x4*)&As[r][c4] = o;
  }
  #pragma unroll
  for (int it = 0; it < 16; ++it) {          // B^T: 128x128 bf16 LDS
    int i = it * 256 + tid;
    int r = i >> 5, c4 = (i & 31) << 2;
    *(bf16x4*)&Bs[r][c4] = *(const bf16x4*)(Bt + (size_t)r * DH + c4);
  }
  __syncthreads();

  const int lane = tid & 63, w = tid >> 6;
  const int mrow = w * 16 + (lane & 15);
  const int kq = (lane >> 4) << 3;

  f32x4 acc[8];
  #pragma unroll
  for (int ct = 0; ct < 8; ++ct) {
    #pragma unroll
    for (int j = 0; j < 4; ++j) acc[ct][j] = 0.f;
  }
  #pragma unroll
  for (int ks = 0; ks < 4; ++ks) {
    bf16x8 a = *(const bf16x8*)&As[mrow][ks * 32 + kq];
    #pragma unroll
    for (int ct = 0; ct < 8; ++ct) {
      bf16x8 b = *(const bf16x8*)&Bs[ct * 16 + (lane & 15)][ks * 32 + kq];
      acc[ct] = __builtin_amdgcn_mfma_f32_16x16x32_bf16(a, b, acc[ct], 0, 0, 0);
    }
  }

  #pragma unroll
  for (int reg = 0; reg < 4; ++reg) {
    int t = row0 + w * 16 + ((lane >> 4) << 2) + reg;
    if (t < Mrows) {
      int rl = role[t];
      const float* gr = gv + rl * DH;
      const float* br = bias ? (bias + rl * DH) : nullptr;
      #pragma unroll
      for (int ct = 0; ct < 8; ++ct) {
        int col = ct * 16 + (lane & 15);
        float v = acc[ct][reg];
        Xt[(size_t)t * DH + col] = (bf16)v;                       // raw xt (for self-transform)
        float mv = v * gr[col] + (br ? br[col] : 0.f);            // gated message (+bias)
        Mo[(size_t)t * DH + col] = (bf16)mv;
      }
    }
  }
}

struct SelfArgs { const bf16* Xt[5]; const bf16* St[5]; float* Ag[5]; };

__global__ __launch_bounds__(256) void gemm_self_kernel(SelfArgs args, const int* __restrict__ perm,
                                                        const int* __restrict__ rsort, int Mrows)
{
  const int cv = blockIdx.y;
  const bf16* __restrict__ Xt  = args.Xt[cv];
  const bf16* __restrict__ Stb = args.St[cv];
  float* __restrict__ Ag = args.Ag[cv];

  __shared__ alignas(16) bf16 As[64][136];
  __shared__ alignas(16) bf16 Bs[128][136];

  const int tid = threadIdx.x;
  const int row0 = blockIdx.x * 64;
  const int lane = tid & 63, w = tid >> 6;

  int r0 = rsort[row0];
  int r1 = rsort[min(row0 + 63, Mrows - 1)];

  f32x4 acc[8];
  #pragma unroll
  for (int ct = 0; ct < 8; ++ct) {
    #pragma unroll
    for (int j = 0; j < 4; ++j) acc[ct][j] = 0.f;
  }

  for (int rr = r0; rr <= r1; ++rr) {        // 1 pass per block unless role-boundary straddle
    #pragma unroll
    for (int it = 0; it < 8; ++it) {         // masked gathered A (rows with role!=rr -> 0)
      int i = it * 256 + tid;
      int r = i >> 5, c4 = (i & 31) << 2;
      int t = row0 + r;
      bf16x4 v; v[0] = v[1] = v[2] = v[3] = (bf16)0.f;
      if (t < Mrows && rsort[t] == rr) v = *(const bf16x4*)(Xt + (size_t)perm[t] * DH + c4);
      *(bf16x4*)&As[r][c4] = v;
    }
    const bf16* Bt = Stb + (size_t)rr * (DH * DH);
    #pragma unroll
    for (int it = 0; it < 16; ++it) {
      int i = it * 256 + tid;
      int r = i >> 5, c4 = (i & 31) << 2;
      *(bf16x4*)&Bs[r][c4] = *(const bf16x4*)(Bt + (size_t)r * DH + c4);
    }
    __syncthreads();
    const int mrow = w * 16 + (lane & 15);
    const int kq = (lane >> 4) << 3;
    #pragma unroll
    for (int ks = 0; ks < 4; ++ks) {
      bf16x8 a = *(const bf16x8*)&As[mrow][ks * 32 + kq];
      #pragma unroll
      for (int ct = 0; ct < 8; ++ct) {
        bf16x8 b = *(const bf16x8*)&Bs[ct * 16 + (lane & 15)][ks * 32 + kq];
        acc[ct] = __builtin_amdgcn_mfma_f32_16x16x32_bf16(a, b, acc[ct], 0, 0, 0);
      }
    }
    __syncthreads();
  }

  #pragma unroll
  for (int reg = 0; reg < 4; ++reg) {
    int t = row0 + w * 16 + ((lane >> 4) << 2) + reg;
    if (t < Mrows) {
      int node = perm[t];
      #pragma unroll
      for (int ct = 0; ct < 8; ++ct) {
        int col = ct * 16 + (lane & 15);
        Ag[(size_t)node * DH + col] += acc[ct][reg];   // single writer per element
      }
    }
  }
}

// ---------------- aggregation (wave per node, CSR) ----------------
struct Agg5Args {
  const bf16* m0; const bf16* m1; const bf16* m2; const bf16* m3; const bf16* m4;
  float* a0; float* a1; float* a2; float* a3; float* a4;
};

__global__ __launch_bounds__(256) void agg5_kernel(Agg5Args ag, const int* __restrict__ off,
                                                   const int* __restrict__ ssrc, int N)
{
  int node = blockIdx.x * 4 + (threadIdx.x >> 6);
  if (node >= N) return;
  int lane = threadIdx.x & 63;
  int s = off[node], e = off[node + 1];
  int c2 = lane << 1;
  float x0 = 0, y0 = 0, x1 = 0, y1 = 0, x2 = 0, y2 = 0, x3 = 0, y3 = 0, x4 = 0, y4 = 0;
  for (int i = s; i < e; ++i) {
    int base = ssrc[i] * DH + c2;
    bf16x2 v0 = *(const bf16x2*)(ag.m0 + base);
    bf16x2 v1 = *(const bf16x2*)(ag.m1 + base);
    bf16x2 v2 = *(const bf16x2*)(ag.m2 + base);
    bf16x2 v3 = *(const bf16x2*)(ag.m3 + base);
    bf16x2 v4 = *(const bf16x2*)(ag.m4 + base);
    x0 += (float)v0[0]; y0 += (float)v0[1];
    x1 += (float)v1[0]; y1 += (float)v1[1];
    x2 += (float)v2[0]; y2 += (float)v2[1];
    x3 += (float)v3[0]; y3 += (float)v3[1];
    x4 += (float)v4[0]; y4 += (float)v4[1];
  }
  float inv = 1.0f / (float)(e - s);
  int ob = node * DH + c2;
  *(float2*)(ag.a0 + ob) = make_float2(x0 * inv, y0 * inv);
  *(float2*)(ag.a1 + ob) = make_float2(x1 * inv, y1 * inv);
  *(float2*)(ag.a2 + ob) = make_float2(x2 * inv, y2 * inv);
  *(float2*)(ag.a3 + ob) = make_float2(x3 * inv, y3 * inv);
  *(float2*)(ag.a4 + ob) = make_float2(x4 * inv, y4 * inv);
}

__global__ __launch_bounds__(256) void agg1_kernel(const bf16* __restrict__ m, const int* __restrict__ off,
                                                   const int* __restrict__ ssrc, float* __restrict__ a, int N)
{
  int node = blockIdx.x * 4 + (threadIdx.x >> 6);
  if (node >= N) return;
  int lane = threadIdx.x & 63;
  int s = off[node], e = off[node + 1];
  int c2 = lane << 1;
  float ax = 0, ay = 0;
  for (int i = s; i < e; ++i) {
    int base = ssrc[i] * DH + c2;
    bf16x2 v = *(const bf16x2*)(m + base);
    ax += (float)v[0]; ay += (float)v[1];
  }
  float inv = 1.0f / (float)(e - s);
  *(float2*)(a + node * DH + c2) = make_float2(ax * inv, ay * inv);
}

// ---------------- pointwise combines ----------------
// in-place: z->a_xz, q=r*h->a_xr, txh=relu(a_xh)->a_xh
__global__ __launch_bounds__(256) void combine1_kernel(float* __restrict__ a_xz, const float* __restrict__ a_hz,
                                                       float* __restrict__ a_xr, const float* __restrict__ a_hr,
                                                       float* __restrict__ a_xh, const float* __restrict__ hprev,
                                                       int total4)
{
  int i = blockIdx.x * 256 + threadIdx.x;
  if (i >= total4) return;
  float4 vz  = ((const float4*)a_xz)[i];
  float4 vhz = ((const float4*)a_hz)[i];
  float4 vr  = ((const float4*)a_xr)[i];
  float4 vhr = ((const float4*)a_hr)[i];
  float4 vh  = ((const float4*)a_xh)[i];
  float4 hp  = ((const float4*)hprev)[i];
  float4 zz, qq, tt;
  { float z = sigmoidf_(reluf_(vz.x) + reluf_(vhz.x)); float rg = sigmoidf_(reluf_(vr.x) + reluf_(vhr.x)); zz.x = z; qq.x = rg * hp.x; tt.x = reluf_(vh.x); }
  { float z = sigmoidf_(reluf_(vz.y) + reluf_(vhz.y)); float rg = sigmoidf_(reluf_(vr.y) + reluf_(vhr.y)); zz.y = z; qq.y = rg * hp.y; tt.y = reluf_(vh.y); }
  { float z = sigmoidf_(reluf_(vz.z) + reluf_(vhz.z)); float rg = sigmoidf_(reluf_(vr.z) + reluf_(vhr.z)); zz.z = z; qq.z = rg * hp.z; tt.z = reluf_(vh.z); }
  { float z = sigmoidf_(reluf_(vz.w) + reluf_(vhz.w)); float rg = sigmoidf_(reluf_(vr.w) + reluf_(vhr.w)); zz.w = z; qq.w = rg * hp.w; tt.w = reluf_(vh.w); }
  ((float4*)a_xz)[i] = zz;
  ((float4*)a_xr)[i] = qq;
  ((float4*)a_xh)[i] = tt;
}

__global__ __launch_bounds__(256) void combine2_kernel(const float* __restrict__ zbuf, const float* __restrict__ txh,
                                                       const float* __restrict__ ahh, const float* __restrict__ hprev,
                                                       float* __restrict__ out, int total4)
{
  int i = blockIdx.x * 256 + threadIdx.x;
  if (i >= total4) return;
  float4 z  = ((const float4*)zbuf)[i];
  float4 t  = ((const float4*)txh)[i];
  float4 a  = ((const float4*)ahh)[i];
  float4 hp = ((const float4*)hprev)[i];
  float4 o;
  o.x = z.x * hp.x + (1.f - z.x) * tanhf(t.x + reluf_(a.x));
  o.y = z.y * hp.y + (1.f - z.y) * tanhf(t.y + reluf_(a.y));
  o.z = z.z * hp.z + (1.f - z.z) * tanhf(t.z + reluf_(a.z));
  o.w = z.w * hp.w + (1.f - z.w) * tanhf(t.w + reluf_(a.w));
  ((float4*)out)[i] = o;
}

// ---------------- host ----------------
extern "C" void kernel_launch(void* const* d_in, const int* in_sizes, int n_in,
                              void* d_out, int out_size, void* d_ws, size_t ws_size,
                              hipStream_t stream)
{
  (void)n_in; (void)out_size; (void)ws_size;
  const float* x    = (const float*)d_in[0];
  const float* h    = (const float*)d_in[1];
  const int*   ei   = (const int*)d_in[2];
  const int*   role = (const int*)d_in[3];
  const int N = in_sizes[0] / DH;
  const int E = in_sizes[2] / 2;
  const int Etot = E + N;

  // conv order: 0 xz, 1 hz, 2 xr, 3 hr, 4 xh, 5 hh
  static const int Wi[6]  = {4, 9, 13, 18, 22, 27};
  static const int Wgi[6] = {5, 10, 14, 19, 23, 28};
  static const int bgi[6] = {6, 11, 15, 20, 24, 29};
  static const int Si[6]  = {7, 12, 16, 21, 25, 30};
  static const int bi[6]  = {8, -1, 17, -1, 26, -1};

  char* p = (char*)d_ws;
  auto alloc = [&](size_t bytes) -> char* {
    char* r = p;
    p += (bytes + 255) & ~(size_t)255;
    return r;
  };
  const size_t NF = (size_t)N * DH;

  float* aggr[5];
  for (int c = 0; c < 5; ++c) aggr[c] = (float*)alloc(NF * 4);
  bf16* xt[5]; bf16* mm[5];
  for (int c = 0; c < 5; ++c) xt[c] = (bf16*)alloc(NF * 2);
  for (int c = 0; c < 5; ++c) mm[c] = (bf16*)alloc(NF * 2);
  float* gbuf = (float*)alloc(6 * 384 * 4);
  bf16* wst   = (bf16*)alloc((size_t)24 * DH * DH * 2);
  int* cnt    = (int*)alloc((size_t)N * 4);
  int* off    = (int*)alloc((size_t)(N + 1) * 4);
  int* fill   = (int*)alloc((size_t)N * 4);
  int* ssrc   = (int*)alloc((size_t)Etot * 4);
  int* rolecnt  = (int*)alloc(64);
  int* rolefill = (int*)alloc(64);
  int* perm   = (int*)alloc((size_t)N * 4);
  int* rsort  = (int*)alloc((size_t)N * 4);

  hipMemsetAsync(cnt, 0, (size_t)N * 4, stream);
  hipMemsetAsync(rolecnt, 0, 16, stream);

  WPtrs wp;
  for (int c = 0; c < 6; ++c) { wp.W[c] = (const float*)d_in[Wi[c]]; wp.S[c] = (const float*)d_in[Si[c]]; }
  transpose_cast_kernel<<<24 * 64, 256, 0, stream>>>(wp, wst);

  GateP gp;
  for (int c = 0; c < 6; ++c) { gp.Wg[c] = (const float*)d_in[Wgi[c]]; gp.bg[c] = (const float*)d_in[bgi[c]]; }
  gates_kernel<<<9, 256, 0, stream>>>(gp, gbuf);

  int egrid = (Etot + 255) / 256;
  hist_kernel<<<egrid, 256, 0, stream>>>(ei, cnt, E, N);
  scan_kernel<<<1, 1024, 0, stream>>>(cnt, off, N);
  hipMemcpyAsync(fill, off, (size_t)N * 4, hipMemcpyDeviceToDevice, stream);
  scatter_kernel<<<egrid, 256, 0, stream>>>(ei, fill, ssrc, E, N);

  int ngrid = (N + 255) / 256;
  rolehist_kernel<<<ngrid, 256, 0, stream>>>(role, rolecnt, N);
  roleoff_kernel<<<1, 1, 0, stream>>>(rolecnt, rolefill);
  permscatter_kernel<<<ngrid, 256, 0, stream>>>(role, rolefill, perm, rsort, N);

  const int mtiles = (N + 63) / 64;

  // ---- pass 1: xz, hz, xr, hr, xh ----
  XtArgs xa;
  const float* Ain[5] = {x, h, x, h, x};
  for (int c = 0; c < 5; ++c) {
    xa.A[c]    = Ain[c];
    xa.Bt[c]   = wst + (size_t)c * DH * DH;
    xa.g[c]    = gbuf + c * 384;
    xa.bias[c] = (bi[c] >= 0) ? (const float*)d_in[bi[c]] : nullptr;
    xa.Xt[c]   = xt[c];
    xa.Mo[c]   = mm[c];
  }
  gemm_xt_kernel<<<dim3(mtiles, 5), 256, 0, stream>>>(xa, role, N);

  Agg5Args ag = { mm[0], mm[1], mm[2], mm[3], mm[4], aggr[0], aggr[1], aggr[2], aggr[3], aggr[4] };
  agg5_kernel<<<(N + 3) / 4, 256, 0, stream>>>(ag, off, ssrc, N);

  SelfArgs sa;
  for (int c = 0; c < 5; ++c) {
    sa.Xt[c] = xt[c];
    sa.St[c] = wst + (size_t)(6 + c * 3) * DH * DH;
    sa.Ag[c] = aggr[c];
  }
  gemm_self_kernel<<<dim3(mtiles, 5), 256, 0, stream>>>(sa, perm, rsort, N);

  int total4 = (int)(NF / 4);
  combine1_kernel<<<(total4 + 255) / 256, 256, 0, stream>>>(aggr[0], aggr[1], aggr[2], aggr[3], aggr[4], h, total4);

  // ---- pass 2: hh on q (q lives in aggr[2]); reuse xt[0]/mm[0]/aggr[1] ----
  XtArgs xa2 = {};
  xa2.A[0]    = aggr[2];
  xa2.Bt[0]   = wst + (size_t)5 * DH * DH;
  xa2.g[0]    = gbuf + 5 * 384;
  xa2.bias[0] = nullptr;
  xa2.Xt[0]   = xt[0];
  xa2.Mo[0]   = mm[0];
  gemm_xt_kernel<<<dim3(mtiles, 1), 256, 0, stream>>>(xa2, role, N);

  agg1_kernel<<<(N + 3) / 4, 256, 0, stream>>>(mm[0], off, ssrc, aggr[1], N);

  SelfArgs sa2 = {};
  sa2.Xt[0] = xt[0];
  sa2.St[0] = wst + (size_t)(6 + 15) * DH * DH;
  sa2.Ag[0] = aggr[1];
  gemm_self_kernel<<<dim3(mtiles, 1), 256, 0, stream>>>(sa2, perm, rsort, N);

  combine2_kernel<<<(total4 + 255) / 256, 256, 0, stream>>>(aggr[0], aggr[4], aggr[1], h, (float*)d_out, total4);
}

// Round 2
// 1115.690 us; speedup vs baseline: 1.0603x; 1.0603x over previous
//
#include <hip/hip_runtime.h>

// GraphGRU on MI355X — round 2: gather/GEMM commutation.
//   aggr_c = (Ucat/deg) @ Wmod_c + Σ_r (cnt_r/deg)·b_c[r] ;  self_c = A_c @ P_c[role]
//   where Ucat = role-bucketed neighbor-sum of raw A (x|h|q), Wmod folds gate g into W,
//   P_c[r] = W_c @ S_c[r]. Gather reads raw bf16 inputs (512 B/edge pass1, 256 B/edge pass2)
//   instead of 5 precomputed message arrays (1280 B/edge) — 2.5x less gather traffic,
//   25.6 MB working set (LLC-resident). Each conv = one K=512 MFMA GEMM (384 Wmod + 128
//   role-selected P via role-sorted perm; role uniform per 64-row block except straddles).

typedef __bf16 bf16;
typedef __bf16 bf16x2 __attribute__((ext_vector_type(2)));
typedef __bf16 bf16x4 __attribute__((ext_vector_type(4)));
typedef __bf16 bf16x8 __attribute__((ext_vector_type(8)));
typedef float  f32x4  __attribute__((ext_vector_type(4)));

#define DH 128

__device__ __forceinline__ float sigmoidf_(float x) { return 1.0f / (1.0f + expf(-x)); }
__device__ __forceinline__ float bflo_(unsigned u) { return __uint_as_float(u << 16); }
__device__ __forceinline__ float bfhi_(unsigned u) { return __uint_as_float(u & 0xffff0000u); }

// ---------------- prep ----------------
// xh[node][256] bf16 : cols 0-127 = x, 128-255 = h
__global__ __launch_bounds__(256) void prep_xh_kernel(const float* __restrict__ x, const float* __restrict__ h,
                                                      bf16* __restrict__ xh, int N)
{
  int g = blockIdx.x * 256 + threadIdx.x;          // float4 groups over N*128
  if (g >= N * 32) return;
  int node = g >> 5, coff = (g & 31) << 2;
  float4 xv = ((const float4*)x)[g];
  float4 hv = ((const float4*)h)[g];
  bf16x4 xo; xo[0] = (bf16)xv.x; xo[1] = (bf16)xv.y; xo[2] = (bf16)xv.z; xo[3] = (bf16)xv.w;
  bf16x4 ho; ho[0] = (bf16)hv.x; ho[1] = (bf16)hv.y; ho[2] = (bf16)hv.z; ho[3] = (bf16)hv.w;
  *(bf16x4*)&xh[node * 256 + coff] = xo;
  *(bf16x4*)&xh[node * 256 + 128 + coff] = ho;
}

struct PrepW { const float* W[6]; const float* Wg[6]; const float* bg[6]; };

// Wmt[cv][col][384] bf16, Wmt[cv][col][r*128+k] = W_cv[k][col] * sigmoid(Wg[r][col]+bg[r][col])
__global__ __launch_bounds__(256) void prep_wmod_kernel(PrepW pw, bf16* __restrict__ Wmt)
{
  int idx = blockIdx.x * 256 + threadIdx.x;        // 6*128*384 = 294912
  if (idx >= 294912) return;
  int cv = idx / 49152, rem = idx % 49152;
  int col = rem / 384, kk = rem % 384;
  int r = kk >> 7, k = kk & 127;
  float g = sigmoidf_(pw.Wg[cv][r * 128 + col] + pw.bg[cv][r * 128 + col]);
  Wmt[idx] = (bf16)(pw.W[cv][k * 128 + col] * g);
}

struct PrepP { const float* W[6]; const float* S[6]; };

// Pt[cv][r][col][k] bf16 = (W_cv @ S_cv[r])[k][col]
__global__ __launch_bounds__(128) void prep_p_kernel(PrepP pp, bf16* __restrict__ Pt)
{
  int b = blockIdx.x;                              // 6*3*128 = 2304
  int cv = b / 384, rem = b % 384;
  int r = rem >> 7, k = rem & 127;
  int col = threadIdx.x;
  const float* W = pp.W[cv];
  const float* S = pp.S[cv] + (size_t)r * DH * DH;
  float sum = 0.f;
  #pragma unroll 4
  for (int j = 0; j < DH; ++j) sum += W[k * DH + j] * S[j * DH + col];
  Pt[(size_t)(cv * 3 + r) * (DH * DH) + col * DH + k] = (bf16)sum;
}

// ---------------- CSR build ----------------
__global__ __launch_bounds__(256) void hist_kernel(const int* __restrict__ ei, int* __restrict__ cnt,
                                                   int E, int N)
{
  int i = blockIdx.x * 256 + threadIdx.x;
  if (i < E + N) {
    int c = (i < E) ? ei[E + i] : (i - E);
    atomicAdd(&cnt[c], 1);
  }
}

__global__ __launch_bounds__(1024) void scan_kernel(const int* __restrict__ cnt, int* __restrict__ off, int n)
{
  __shared__ int wsum[17];
  int t = threadIdx.x, lane = t & 63, w = t >> 6;
  if (t == 0) { wsum[16] = 0; off[0] = 0; }
  __syncthreads();
  for (int base = 0; base < n; base += 1024) {
    int carry = wsum[16];
    int idx = base + t;
    int v = (idx < n) ? cnt[idx] : 0;
    int s = v;
    #pragma unroll
    for (int d = 1; d < 64; d <<= 1) { int u = __shfl_up(s, d); if (lane >= d) s += u; }
    if (lane == 63) wsum[w] = s;
    __syncthreads();
    if (w == 0 && lane < 16) {
      int ws = wsum[lane];
      #pragma unroll
      for (int d = 1; d < 16; d <<= 1) { int u = __shfl_up(ws, d); if (lane >= d) ws += u; }
      wsum[lane] = ws;
    }
    __syncthreads();
    int inc = carry + ((w > 0) ? wsum[w - 1] : 0) + s;
    if (idx < n) off[idx + 1] = inc;
    __syncthreads();
    if (t == 0) wsum[16] = carry + wsum[15];
    __syncthreads();
  }
}

// ssrc packs src | role(src)<<26
__global__ __launch_bounds__(256) void scatter_kernel(const int* __restrict__ ei, const int* __restrict__ role,
                                                      int* __restrict__ fill, int* __restrict__ ssrc, int E, int N)
{
  int i = blockIdx.x * 256 + threadIdx.x;
  if (i < E + N) {
    int c, r;
    if (i < E) { c = ei[E + i]; r = ei[i]; } else { c = i - E; r = i - E; }
    int pz = atomicAdd(&fill[c], 1);
    ssrc[pz] = r | (role[r] << 26);
  }
}

// ---------------- role sort of nodes ----------------
__global__ __launch_bounds__(256) void rolehist_kernel(const int* __restrict__ role, int* __restrict__ rolecnt, int N)
{
  int i = blockIdx.x * 256 + threadIdx.x;
  int lane = threadIdx.x & 63;
  int r = (i < N) ? role[i] : -1;
  #pragma unroll
  for (int rr = 0; rr < 3; ++rr) {
    unsigned long long mask = __ballot(r == rr);
    if (lane == 0 && mask) atomicAdd(&rolecnt[rr], __popcll(mask));
  }
}

__global__ void roleoff_kernel(const int* __restrict__ rolecnt, int* __restrict__ rolefill)
{
  rolefill[0] = 0;
  rolefill[1] = rolecnt[0];
  rolefill[2] = rolecnt[0] + rolecnt[1];
}

__global__ __launch_bounds__(256) void permscatter_kernel(const int* __restrict__ role, int* __restrict__ rolefill,
                                                          int* __restrict__ perm, int* __restrict__ rsort, int N)
{
  int i = blockIdx.x * 256 + threadIdx.x;
  int lane = threadIdx.x & 63;
  int r = (i < N) ? role[i] : -1;
  #pragma unroll
  for (int rr = 0; rr < 3; ++rr) {
    unsigned long long mask = __ballot(r == rr);
    if (!mask) continue;
    int base = 0;
    if (lane == 0) base = atomicAdd(&rolefill[rr], __popcll(mask));
    base = __shfl(base, 0);
    if (r == rr) {
      int rank = (int)__popcll(mask & ((1ull << lane) - 1ull));
      perm[base + rank] = i;
      rsort[base + rank] = rr;
    }
  }
}

// ---------------- gathers (wave per dst node) ----------------
// Ux[node][r*128+k] = (Σ_{nbr role=r} x[nbr][k]) / deg  (bf16), same for Uh.
// cntf[node] = (c0/deg, c1/deg, c2/deg, deg)
__global__ __launch_bounds__(256) void gather_xh_kernel(const bf16* __restrict__ xh, const int* __restrict__ off,
                                                        const int* __restrict__ ssrc, bf16* __restrict__ Ux,
                                                        bf16* __restrict__ Uh, float4* __restrict__ cntf, int N)
{
  int node = blockIdx.x * 4 + (threadIdx.x >> 6);
  if (node >= N) return;
  int lane = threadIdx.x & 63;
  int s = off[node], e = off[node + 1];
  float x0a = 0, x0b = 0, x1a = 0, x1b = 0, x2a = 0, x2b = 0;
  float h0a = 0, h0b = 0, h1a = 0, h1b = 0, h2a = 0, h2b = 0;
  int c0 = 0, c1 = 0;
  for (int i = s; i < e; ++i) {
    int vv = __builtin_amdgcn_readfirstlane(ssrc[i]);
    int src = vv & 0x03FFFFFF;
    int r = vv >> 26;
    const unsigned* p = (const unsigned*)(xh + (size_t)src * 256);
    unsigned ax = p[lane];
    unsigned ah = p[64 + lane];
    float fx0 = bflo_(ax), fx1 = bfhi_(ax);
    float fh0 = bflo_(ah), fh1 = bfhi_(ah);
    if (r == 0)      { x0a += fx0; x0b += fx1; h0a += fh0; h0b += fh1; c0++; }
    else if (r == 1) { x1a += fx0; x1b += fx1; h1a += fh0; h1b += fh1; c1++; }
    else             { x2a += fx0; x2b += fx1; h2a += fh0; h2b += fh1; }
  }
  int deg = e - s;
  float inv = 1.0f / (float)deg;
  int c2 = lane << 1;
  size_t ob = (size_t)node * 384 + c2;
  bf16x2 o;
  o[0] = (bf16)(x0a * inv); o[1] = (bf16)(x0b * inv); *(bf16x2*)&Ux[ob] = o;
  o[0] = (bf16)(x1a * inv); o[1] = (bf16)(x1b * inv); *(bf16x2*)&Ux[ob + 128] = o;
  o[0] = (bf16)(x2a * inv); o[1] = (bf16)(x2b * inv); *(bf16x2*)&Ux[ob + 256] = o;
  o[0] = (bf16)(h0a * inv); o[1] = (bf16)(h0b * inv); *(bf16x2*)&Uh[ob] = o;
  o[0] = (bf16)(h1a * inv); o[1] = (bf16)(h1b * inv); *(bf16x2*)&Uh[ob + 128] = o;
  o[0] = (bf16)(h2a * inv); o[1] = (bf16)(h2b * inv); *(bf16x2*)&Uh[ob + 256] = o;
  if (lane == 0)
    cntf[node] = make_float4(c0 * inv, c1 * inv, (deg - c0 - c1) * inv, (float)deg);
}

__global__ __launch_bounds__(256) void gather_q_kernel(const bf16* __restrict__ q, const int* __restrict__ off,
                                                       const int* __restrict__ ssrc, bf16* __restrict__ Uq, int N)
{
  int node = blockIdx.x * 4 + (threadIdx.x >> 6);
  if (node >= N) return;
  int lane = threadIdx.x & 63;
  int s = off[node], e = off[node + 1];
  float u0a = 0, u0b = 0, u1a = 0, u1b = 0, u2a = 0, u2b = 0;
  for (int i = s; i < e; ++i) {
    int vv = __builtin_amdgcn_readfirstlane(ssrc[i]);
    int src = vv & 0x03FFFFFF;
    int r = vv >> 26;
    unsigned aq = ((const unsigned*)(q + (size_t)src * 128))[lane];
    float f0 = bflo_(aq), f1 = bfhi_(aq);
    if (r == 0)      { u0a += f0; u0b += f1; }
    else if (r == 1) { u1a += f0; u1b += f1; }
    else             { u2a += f0; u2b += f1; }
  }
  float inv = 1.0f / (float)(e - s);
  int c2 = lane << 1;
  size_t ob = (size_t)node * 384 + c2;
  bf16x2 o;
  o[0] = (bf16)(u0a * inv); o[1] = (bf16)(u0b * inv); *(bf16x2*)&Uq[ob] = o;
  o[0] = (bf16)(u1a * inv); o[1] = (bf16)(u1b * inv); *(bf16x2*)&Uq[ob + 128] = o;
  o[0] = (bf16)(u2a * inv); o[1] = (bf16)(u2b * inv); *(bf16x2*)&Uq[ob + 256] = o;
}

// ---------------- fused conv GEMM: out = relu(U@Wmod + bias-term + A@P[role]) ----------------
struct GemmArgs {
  const bf16* U[5];       // [N][384] (already /deg)
  const bf16* A[5];       // row base (xh, xh+128, or q)
  int astride[5];
  const bf16* Wm[5];      // [128 col][384]
  const bf16* Pt[5];      // [3][128 col][128]
  const float* bias[5];   // (R,DH) or null
  bf16* out[5];           // [N][128], relu'd
};

__device__ __forceinline__ void mfma_tile_(const bf16 (&As)[64][136], const bf16 (&Bs)[128][136],
                                           f32x4 (&acc)[8], int lane, int w)
{
  const int mrow = w * 16 + (lane & 15);
  const int kq = (lane >> 4) << 3;
  #pragma unroll
  for (int ks = 0; ks < 4; ++ks) {
    bf16x8 a = *(const bf16x8*)&As[mrow][ks * 32 + kq];
    #pragma unroll
    for (int ct = 0; ct < 8; ++ct) {
      bf16x8 b = *(const bf16x8*)&Bs[ct * 16 + (lane & 15)][ks * 32 + kq];
      acc[ct] = __builtin_amdgcn_mfma_f32_16x16x32_bf16(a, b, acc[ct], 0, 0, 0);
    }
  }
}

__global__ __launch_bounds__(256) void gemm_conv_kernel(GemmArgs ga, const int* __restrict__ perm,
                                                        const int* __restrict__ rsort,
                                                        const float4* __restrict__ cntf, int N)
{
  const int cv = blockIdx.y;
  const bf16* __restrict__ U  = ga.U[cv];
  const bf16* __restrict__ A  = ga.A[cv];
  const int astr = ga.astride[cv];
  const bf16* __restrict__ Wm = ga.Wm[cv];
  const bf16* __restrict__ Pt = ga.Pt[cv];
  const float* __restrict__ bias = ga.bias[cv];
  bf16* __restrict__ out = ga.out[cv];

  __shared__ alignas(16) bf16 As[64][136];
  __shared__ alignas(16) bf16 Bs[128][136];

  const int tid = threadIdx.x;
  const int row0 = blockIdx.x * 64;
  const int lane = tid & 63, w = tid >> 6;

  f32x4 acc[8];
  #pragma unroll
  for (int ct = 0; ct < 8; ++ct) {
    #pragma unroll
    for (int j = 0; j < 4; ++j) acc[ct][j] = 0.f;
  }

  // K chunks 0..2: aggregation part (U @ Wmod)
  for (int chunk = 0; chunk < 3; ++chunk) {
    #pragma unroll
    for (int it = 0; it < 8; ++it) {
      int i = it * 256 + tid;
      int r = i >> 5, c4 = (i & 31) << 2;
      int t = row0 + r;
      bf16x4 v; v[0] = v[1] = v[2] = v[3] = (bf16)0.f;
      if (t < N) v = *(const bf16x4*)(U + (size_t)perm[t] * 384 + chunk * 128 + c4);
      *(bf16x4*)&As[r][c4] = v;
    }
    #pragma unroll
    for (int it = 0; it < 16; ++it) {
      int i = it * 256 + tid;
      int r = i >> 5, c4 = (i & 31) << 2;
      *(bf16x4*)&Bs[r][c4] = *(const bf16x4*)(Wm + (size_t)r * 384 + chunk * 128 + c4);
    }
    __syncthreads();
    mfma_tile_(As, Bs, acc, lane, w);
    __syncthreads();
  }

  // K chunk 3: self part (A @ P[role]); role uniform per block except straddles
  int r0 = rsort[row0];
  int r1 = rsort[min(row0 + 63, N - 1)];
  for (int rr = r0; rr <= r1; ++rr) {
    #pragma unroll
    for (int it = 0; it < 8; ++it) {
      int i = it * 256 + tid;
      int r = i >> 5, c4 = (i & 31) << 2;
      int t = row0 + r;
      bf16x4 v; v[0] = v[1] = v[2] = v[3] = (bf16)0.f;
      if (t < N && rsort[t] == rr) v = *(const bf16x4*)(A + (size_t)perm[t] * astr + c4);
      *(bf16x4*)&As[r][c4] = v;
    }
    const bf16* Pb = Pt + (size_t)rr * (DH * DH);
    #pragma unroll
    for (int it = 0; it < 16; ++it) {
      int i = it * 256 + tid;
      int r = i >> 5, c4 = (i & 31) << 2;
      *(bf16x4*)&Bs[r][c4] = *(const bf16x4*)(Pb + (size_t)r * DH + c4);
    }
    __syncthreads();
    mfma_tile_(As, Bs, acc, lane, w);
    __syncthreads();
  }

  // epilogue
  int nodes[4];
  float4 cf[4];
  #pragma unroll
  for (int reg = 0; reg < 4; ++reg) {
    int t = row0 + w * 16 + ((lane >> 4) << 2) + reg;
    nodes[reg] = (t < N) ? perm[t] : -1;
    cf[reg] = (nodes[reg] >= 0) ? cntf[nodes[reg]] : make_float4(0, 0, 0, 0);
  }
  #pragma unroll
  for (int ct = 0; ct < 8; ++ct) {
    int col = ct * 16 + (lane & 15);
    float b0 = 0, b1 = 0, b2 = 0;
    if (bias) { b0 = bias[col]; b1 = bias[128 + col]; b2 = bias[256 + col]; }
    #pragma unroll
    for (int reg = 0; reg < 4; ++reg) {
      if (nodes[reg] >= 0) {
        float v = acc[ct][reg] + cf[reg].x * b0 + cf[reg].y * b1 + cf[reg].z * b2;
        out[(size_t)nodes[reg] * 128 + col] = (bf16)fmaxf(v, 0.f);
      }
    }
  }
}

// ---------------- pointwise combines ----------------
__global__ __launch_bounds__(256) void combine1_kernel(const bf16* __restrict__ oxz, const bf16* __restrict__ ohz,
                                                       const bf16* __restrict__ oxr, const bf16* __restrict__ ohr,
                                                       const float* __restrict__ hprev,
                                                       float* __restrict__ zbuf, bf16* __restrict__ qbuf, int total4)
{
  int i = blockIdx.x * 256 + threadIdx.x;
  if (i >= total4) return;
  bf16x4 vz = ((const bf16x4*)oxz)[i];
  bf16x4 vhz = ((const bf16x4*)ohz)[i];
  bf16x4 vr = ((const bf16x4*)oxr)[i];
  bf16x4 vhr = ((const bf16x4*)ohr)[i];
  float4 hp = ((const float4*)hprev)[i];
  float4 zz;
  bf16x4 qq;
  zz.x = sigmoidf_((float)vz[0] + (float)vhz[0]);
  zz.y = sigmoidf_((float)vz[1] + (float)vhz[1]);
  zz.z = sigmoidf_((float)vz[2] + (float)vhz[2]);
  zz.w = sigmoidf_((float)vz[3] + (float)vhz[3]);
  qq[0] = (bf16)(sigmoidf_((float)vr[0] + (float)vhr[0]) * hp.x);
  qq[1] = (bf16)(sigmoidf_((float)vr[1] + (float)vhr[1]) * hp.y);
  qq[2] = (bf16)(sigmoidf_((float)vr[2] + (float)vhr[2]) * hp.z);
  qq[3] = (bf16)(sigmoidf_((float)vr[3] + (float)vhr[3]) * hp.w);
  ((float4*)zbuf)[i] = zz;
  ((bf16x4*)qbuf)[i] = qq;
}

__global__ __launch_bounds__(256) void combine2_kernel(const float* __restrict__ zbuf, const bf16* __restrict__ oxh,
                                                       const bf16* __restrict__ ohh, const float* __restrict__ hprev,
                                                       float* __restrict__ out, int total4)
{
  int i = blockIdx.x * 256 + threadIdx.x;
  if (i >= total4) return;
  float4 z = ((const float4*)zbuf)[i];
  bf16x4 a = ((const bf16x4*)oxh)[i];
  bf16x4 b = ((const bf16x4*)ohh)[i];
  float4 hp = ((const float4*)hprev)[i];
  float4 o;
  o.x = z.x * hp.x + (1.f - z.x) * tanhf((float)a[0] + (float)b[0]);
  o.y = z.y * hp.y + (1.f - z.y) * tanhf((float)a[1] + (float)b[1]);
  o.z = z.z * hp.z + (1.f - z.z) * tanhf((float)a[2] + (float)b[2]);
  o.w = z.w * hp.w + (1.f - z.w) * tanhf((float)a[3] + (float)b[3]);
  ((float4*)out)[i] = o;
}

// ---------------- host ----------------
extern "C" void kernel_launch(void* const* d_in, const int* in_sizes, int n_in,
                              void* d_out, int out_size, void* d_ws, size_t ws_size,
                              hipStream_t stream)
{
  (void)n_in; (void)out_size; (void)ws_size;
  const float* x    = (const float*)d_in[0];
  const float* h    = (const float*)d_in[1];
  const int*   ei   = (const int*)d_in[2];
  const int*   role = (const int*)d_in[3];
  const int N = in_sizes[0] / DH;
  const int E = in_sizes[2] / 2;
  const int Etot = E + N;

  // conv order: 0 xz, 1 hz, 2 xr, 3 hr, 4 xh, 5 hh
  static const int Wi[6]  = {4, 9, 13, 18, 22, 27};
  static const int Wgi[6] = {5, 10, 14, 19, 23, 28};
  static const int bgi[6] = {6, 11, 15, 20, 24, 29};
  static const int Si[6]  = {7, 12, 16, 21, 25, 30};
  static const int bi[6]  = {8, -1, 17, -1, 26, -1};

  char* p = (char*)d_ws;
  auto alloc = [&](size_t bytes) -> char* {
    char* r = p;
    p += (bytes + 255) & ~(size_t)255;
    return r;
  };
  const size_t NF = (size_t)N * DH;

  bf16* xh   = (bf16*)alloc((size_t)N * 256 * 2);
  bf16* Ux   = (bf16*)alloc((size_t)N * 384 * 2);
  bf16* Uh   = (bf16*)alloc((size_t)N * 384 * 2);
  bf16* outs[6];
  for (int c = 0; c < 6; ++c) outs[c] = (bf16*)alloc(NF * 2);
  float* zbuf = (float*)alloc(NF * 4);
  bf16* qbuf  = (bf16*)alloc(NF * 2);
  float4* cntf = (float4*)alloc((size_t)N * 16);
  bf16* Wmt  = (bf16*)alloc((size_t)6 * 128 * 384 * 2);
  bf16* Pt   = (bf16*)alloc((size_t)18 * DH * DH * 2);
  int* cnt   = (int*)alloc((size_t)N * 4);
  int* off   = (int*)alloc((size_t)(N + 1) * 4);
  int* fill  = (int*)alloc((size_t)N * 4);
  int* ssrc  = (int*)alloc((size_t)Etot * 4);
  int* rolecnt  = (int*)alloc(64);
  int* rolefill = (int*)alloc(64);
  int* perm  = (int*)alloc((size_t)N * 4);
  int* rsort = (int*)alloc((size_t)N * 4);

  hipMemsetAsync(cnt, 0, (size_t)N * 4, stream);
  hipMemsetAsync(rolecnt, 0, 16, stream);

  // prep
  int g4 = (N * 32 + 255) / 256;
  prep_xh_kernel<<<g4, 256, 0, stream>>>(x, h, xh, N);

  PrepW pw;
  for (int c = 0; c < 6; ++c) {
    pw.W[c] = (const float*)d_in[Wi[c]];
    pw.Wg[c] = (const float*)d_in[Wgi[c]];
    pw.bg[c] = (const float*)d_in[bgi[c]];
  }
  prep_wmod_kernel<<<1152, 256, 0, stream>>>(pw, Wmt);

  PrepP pp;
  for (int c = 0; c < 6; ++c) { pp.W[c] = (const float*)d_in[Wi[c]]; pp.S[c] = (const float*)d_in[Si[c]]; }
  prep_p_kernel<<<2304, 128, 0, stream>>>(pp, Pt);

  // CSR
  int egrid = (Etot + 255) / 256;
  hist_kernel<<<egrid, 256, 0, stream>>>(ei, cnt, E, N);
  scan_kernel<<<1, 1024, 0, stream>>>(cnt, off, N);
  hipMemcpyAsync(fill, off, (size_t)N * 4, hipMemcpyDeviceToDevice, stream);
  scatter_kernel<<<egrid, 256, 0, stream>>>(ei, role, fill, ssrc, E, N);

  // role sort
  int ngrid = (N + 255) / 256;
  rolehist_kernel<<<ngrid, 256, 0, stream>>>(role, rolecnt, N);
  roleoff_kernel<<<1, 1, 0, stream>>>(rolecnt, rolefill);
  permscatter_kernel<<<ngrid, 256, 0, stream>>>(role, rolefill, perm, rsort, N);

  // pass 1
  gather_xh_kernel<<<(N + 3) / 4, 256, 0, stream>>>(xh, off, ssrc, Ux, Uh, cntf, N);

  const int mtiles = (N + 63) / 64;
  GemmArgs ga;
  const bf16* Ain[5]  = {xh, xh + 128, xh, xh + 128, xh};
  const bf16* Uin[5]  = {Ux, Uh, Ux, Uh, Ux};
  for (int c = 0; c < 5; ++c) {
    ga.U[c] = Uin[c];
    ga.A[c] = Ain[c];
    ga.astride[c] = 256;
    ga.Wm[c] = Wmt + (size_t)c * 128 * 384;
    ga.Pt[c] = Pt + (size_t)(c * 3) * DH * DH;
    ga.bias[c] = (bi[c] >= 0) ? (const float*)d_in[bi[c]] : nullptr;
    ga.out[c] = outs[c];
  }
  gemm_conv_kernel<<<dim3(mtiles, 5), 256, 0, stream>>>(ga, perm, rsort, cntf, N);

  int total4 = (int)(NF / 4);
  combine1_kernel<<<(total4 + 255) / 256, 256, 0, stream>>>(outs[0], outs[1], outs[2], outs[3], h,
                                                            zbuf, qbuf, total4);

  // pass 2: hh conv on q; reuse Ux as Uq
  gather_q_kernel<<<(N + 3) / 4, 256, 0, stream>>>(qbuf, off, ssrc, Ux, N);

  GemmArgs ga2 = {};
  ga2.U[0] = Ux;
  ga2.A[0] = qbuf;
  ga2.astride[0] = 128;
  ga2.Wm[0] = Wmt + (size_t)5 * 128 * 384;
  ga2.Pt[0] = Pt + (size_t)15 * DH * DH;
  ga2.bias[0] = nullptr;
  ga2.out[0] = outs[5];
  gemm_conv_kernel<<<dim3(mtiles, 1), 256, 0, stream>>>(ga2, perm, rsort, cntf, N);

  combine2_kernel<<<(total4 + 255) / 256, 256, 0, stream>>>(zbuf, outs[4], outs[5], h, (float*)d_out, total4);
}

// Round 3
// 973.620 us; speedup vs baseline: 1.2150x; 1.1459x over previous
//
#include <hip/hip_runtime.h>

// GraphGRU on MI355X — round 3: barrier-free streaming MFMA GEMM on role-sorted,
// fragment-ordered operands.
//   A'[rb][kslice16][quad4][lane16][8] bf16, K=512 = [U role-bucketed (384) | self input (128)]
//   B frag-ordered: Wf (gate-folded W, K=384) + Pf[role] (W@S, K=128), streamed from L2.
//   Role regions padded to 64 rows (zeroed) -> role uniform per block, no perm in GEMM.
//   Gathers: unroll-4, 8 row-loads in flight; write U directly into A' (LDS repack).

typedef __bf16 bf16;
typedef __bf16 bf16x4 __attribute__((ext_vector_type(4)));
typedef __bf16 bf16x8 __attribute__((ext_vector_type(8)));
typedef float  f32x4  __attribute__((ext_vector_type(4)));

#define DH 128

__device__ __forceinline__ float sigmoidf_(float x) { return 1.0f / (1.0f + expf(-x)); }
__device__ __forceinline__ float bflo_(unsigned u) { return __uint_as_float(u << 16); }
__device__ __forceinline__ float bfhi_(unsigned u) { return __uint_as_float(u & 0xffff0000u); }

// ---------------- CSR build ----------------
__global__ __launch_bounds__(256) void hist_kernel(const int* __restrict__ ei, int* __restrict__ cnt,
                                                   int E, int N)
{
  int i = blockIdx.x * 256 + threadIdx.x;
  if (i < E + N) {
    int c = (i < E) ? ei[E + i] : (i - E);
    atomicAdd(&cnt[c], 1);
  }
}

__global__ __launch_bounds__(1024) void scan_kernel(const int* __restrict__ cnt, int* __restrict__ off,
                                                    int* __restrict__ fill, int n)
{
  __shared__ int wsum[17];
  int t = threadIdx.x, lane = t & 63, w = t >> 6;
  if (t == 0) { wsum[16] = 0; off[0] = 0; fill[0] = 0; }
  __syncthreads();
  for (int base = 0; base < n; base += 1024) {
    int carry = wsum[16];
    int idx = base + t;
    int v = (idx < n) ? cnt[idx] : 0;
    int s = v;
    #pragma unroll
    for (int d = 1; d < 64; d <<= 1) { int u = __shfl_up(s, d); if (lane >= d) s += u; }
    if (lane == 63) wsum[w] = s;
    __syncthreads();
    if (w == 0 && lane < 16) {
      int ws = wsum[lane];
      #pragma unroll
      for (int d = 1; d < 16; d <<= 1) { int u = __shfl_up(ws, d); if (lane >= d) ws += u; }
      wsum[lane] = ws;
    }
    __syncthreads();
    int inc = carry + ((w > 0) ? wsum[w - 1] : 0) + s;
    if (idx < n) {
      off[idx + 1] = inc;
      if (idx + 1 < n) fill[idx + 1] = inc;
    }
    __syncthreads();
    if (t == 0) wsum[16] = carry + wsum[15];
    __syncthreads();
  }
}

// ssrc packs src | role(src)<<26
__global__ __launch_bounds__(256) void scatter_kernel(const int* __restrict__ ei, const int* __restrict__ role,
                                                      int* __restrict__ fill, int* __restrict__ ssrc, int E, int N)
{
  int i = blockIdx.x * 256 + threadIdx.x;
  if (i < E + N) {
    int c, r;
    if (i < E) { c = ei[E + i]; r = ei[i]; } else { c = i - E; r = i - E; }
    int pz = atomicAdd(&fill[c], 1);
    ssrc[pz] = r | (role[r] << 26);
  }
}

// ---------------- role sort ----------------
__global__ __launch_bounds__(256) void rolehist_kernel(const int* __restrict__ role, int* __restrict__ rolecnt, int N)
{
  int i = blockIdx.x * 256 + threadIdx.x;
  int lane = threadIdx.x & 63;
  int r = (i < N) ? role[i] : -1;
  #pragma unroll
  for (int rr = 0; rr < 3; ++rr) {
    unsigned long long mask = __ballot(r == rr);
    if (lane == 0 && mask) atomicAdd(&rolecnt[rr], __popcll(mask));
  }
}

// roleinfo: {s1, s2, g0s, g0l, g1s, g1l, g2s, g2l}; rolefill: {0, s1, s2}
__global__ void roleoff_kernel(const int* __restrict__ rolecnt, int* __restrict__ rolefill,
                               int* __restrict__ roleinfo)
{
  int c0 = rolecnt[0], c1 = rolecnt[1], c2 = rolecnt[2];
  int s1 = (c0 + 63) & ~63;
  int s2 = s1 + ((c1 + 63) & ~63);
  int mp = s2 + ((c2 + 63) & ~63);
  rolefill[0] = 0; rolefill[1] = s1; rolefill[2] = s2;
  roleinfo[0] = s1; roleinfo[1] = s2;
  roleinfo[2] = c0;      roleinfo[3] = s1 - c0;
  roleinfo[4] = s1 + c1; roleinfo[5] = s2 - s1 - c1;
  roleinfo[6] = s2 + c2; roleinfo[7] = mp - s2 - c2;
}

__global__ __launch_bounds__(256) void permscatter_kernel(const int* __restrict__ role, int* __restrict__ rolefill,
                                                          int* __restrict__ spos, int N)
{
  int i = blockIdx.x * 256 + threadIdx.x;
  int lane = threadIdx.x & 63;
  int r = (i < N) ? role[i] : -1;
  #pragma unroll
  for (int rr = 0; rr < 3; ++rr) {
    unsigned long long mask = __ballot(r == rr);
    if (!mask) continue;
    int base = 0;
    if (lane == 0) base = atomicAdd(&rolefill[rr], __popcll(mask));
    base = __shfl(base, 0);
    if (r == rr) {
      int rank = (int)__popcll(mask & ((1ull << lane) - 1ull));
      spos[i] = base + rank;
    }
  }
}

// zero pad rows of Ax, Ah (Aq aliases Ax, pads preserved). 2 arrays x 3 gaps x 64 rows x 64 chunks.
__global__ __launch_bounds__(256) void zeropad_kernel(const int* __restrict__ roleinfo,
                                                      bf16* __restrict__ Ax, bf16* __restrict__ Ah)
{
  int id = blockIdx.x * 256 + threadIdx.x;   // 24576
  int a = id / 12288, rem = id % 12288;
  int gp = rem / 4096, r2 = rem % 4096;
  int rr = r2 >> 6, c = r2 & 63;
  int gs = roleinfo[2 + gp * 2], gl = roleinfo[3 + gp * 2];
  if (rr < gl) {
    int row = gs + rr;
    size_t unit = (size_t)(row >> 4) * 1024 + c * 16 + (row & 15);
    bf16x8 z = {};
    ((bf16x8*)(a == 0 ? Ax : Ah))[unit] = z;
  }
}

// ---------------- prep ----------------
// xh natural [n][256] (x|h) for gather; self parts (kslices 12..15) of A'x, A'h at sorted rows.
__global__ __launch_bounds__(256) void prep_xh_kernel(const float* __restrict__ x, const float* __restrict__ h,
                                                      const int* __restrict__ spos, bf16* __restrict__ xh,
                                                      bf16* __restrict__ Ax, bf16* __restrict__ Ah, int N)
{
  int g = blockIdx.x * 256 + threadIdx.x;
  if (g >= N * 32) return;
  int n = g >> 5, j = g & 31;
  int t = spos[n];
  int rb = t >> 4, l = t & 15;
  const float* src = (j < 16) ? (x + (size_t)n * 128 + j * 8) : (h + (size_t)n * 128 + (j - 16) * 8);
  float4 v0 = ((const float4*)src)[0];
  float4 v1 = ((const float4*)src)[1];
  bf16x8 o;
  o[0] = (bf16)v0.x; o[1] = (bf16)v0.y; o[2] = (bf16)v0.z; o[3] = (bf16)v0.w;
  o[4] = (bf16)v1.x; o[5] = (bf16)v1.y; o[6] = (bf16)v1.z; o[7] = (bf16)v1.w;
  int j16 = j & 15;
  ((bf16x8*)xh)[(size_t)n * 32 + j] = o;   // natural: x at chunks 0..15, h at 16..31
  size_t unit = (size_t)rb * 1024 + (48 + j16) * 16 + l;
  ((bf16x8*)(j < 16 ? Ax : Ah))[unit] = o;
}

// Wf[cv][kslice12][q4][col128][8]: W[kk][col]*sigmoid(Wg[r][col]+bg[r][col]), k=kslice*32+q*8+j
struct PrepW { const float* W[6]; const float* Wg[6]; const float* bg[6]; };
__global__ __launch_bounds__(256) void prep_wf_kernel(PrepW pw, bf16* __restrict__ Wf)
{
  int idx = blockIdx.x * 256 + threadIdx.x;   // 6*49152
  if (idx >= 294912) return;
  int cv = idx / 49152, pos = idx % 49152;
  int ks4q = pos >> 10;
  int col = (pos >> 3) & 127, j = pos & 7;
  int k = (ks4q >> 2) * 32 + (ks4q & 3) * 8 + j;
  int r = k >> 7, kk = k & 127;
  float g = sigmoidf_(pw.Wg[cv][r * 128 + col] + pw.bg[cv][r * 128 + col]);
  Wf[idx] = (bf16)(pw.W[cv][kk * 128 + col] * g);
}

// Pf[cv][r][ks4][q][col][8] = (W_cv @ S_cv[r])[k'][col], k' = ks*32+q*8+j
struct PrepP { const float* W[6]; const float* S[6]; };
__global__ __launch_bounds__(128) void prep_pf_kernel(PrepP pp, bf16* __restrict__ Pf)
{
  int b = blockIdx.x;                          // 6*3*128
  int cv = b / 384, rem = b % 384;
  int r = rem >> 7, kp = rem & 127;
  int col = threadIdx.x;
  const float* W = pp.W[cv] + (size_t)kp * 128;
  const float* S = pp.S[cv] + (size_t)r * 16384;
  float sum = 0.f;
  #pragma unroll 4
  for (int j2 = 0; j2 < 128; ++j2) sum += W[j2] * S[j2 * 128 + col];
  size_t o = (size_t)(cv * 3 + r) * 16384 + ((size_t)(kp >> 3) * 128 + col) * 8 + (kp & 7);
  Pf[o] = (bf16)sum;
}

// ---------------- gathers ----------------
__global__ __launch_bounds__(256) void gather_xh_kernel(
    const bf16* __restrict__ xh, const int* __restrict__ off, const int* __restrict__ ssrc,
    const int* __restrict__ spos, bf16* __restrict__ Ax, bf16* __restrict__ Ah,
    float4* __restrict__ cntf, int N)
{
  __shared__ alignas(16) bf16 lds[4][768];
  int w = threadIdx.x >> 6, lane = threadIdx.x & 63;
  int node = blockIdx.x * 4 + w;
  bool act = node < N;
  int s = 0, e = 0;
  if (act) { s = off[node]; e = off[node + 1]; }
  float xa0 = 0, xb0 = 0, xa1 = 0, xb1 = 0, xa2 = 0, xb2 = 0;
  float ha0 = 0, hb0 = 0, ha1 = 0, hb1 = 0, ha2 = 0, hb2 = 0;
  int c0 = 0, c1 = 0;

  auto accum = [&](int v, unsigned ax, unsigned ah) {
    int r = ((unsigned)v) >> 26;
    float f0 = bflo_(ax), f1 = bfhi_(ax), g0 = bflo_(ah), g1 = bfhi_(ah);
    if (r == 0)      { xa0 += f0; xb0 += f1; ha0 += g0; hb0 += g1; c0++; }
    else if (r == 1) { xa1 += f0; xb1 += f1; ha1 += g0; hb1 += g1; c1++; }
    else             { xa2 += f0; xb2 += f1; ha2 += g0; hb2 += g1; }
  };

  int i = s;
  for (; i + 4 <= e; i += 4) {
    int v0 = ssrc[i], v1 = ssrc[i + 1], v2 = ssrc[i + 2], v3 = ssrc[i + 3];
    const unsigned* p0 = (const unsigned*)xh + ((size_t)(v0 & 0x03FFFFFF) << 7);
    const unsigned* p1 = (const unsigned*)xh + ((size_t)(v1 & 0x03FFFFFF) << 7);
    const unsigned* p2 = (const unsigned*)xh + ((size_t)(v2 & 0x03FFFFFF) << 7);
    const unsigned* p3 = (const unsigned*)xh + ((size_t)(v3 & 0x03FFFFFF) << 7);
    unsigned ax0 = p0[lane], ah0 = p0[64 + lane];
    unsigned ax1 = p1[lane], ah1 = p1[64 + lane];
    unsigned ax2 = p2[lane], ah2 = p2[64 + lane];
    unsigned ax3 = p3[lane], ah3 = p3[64 + lane];
    accum(v0, ax0, ah0); accum(v1, ax1, ah1); accum(v2, ax2, ah2); accum(v3, ax3, ah3);
  }
  for (; i < e; ++i) {
    int v = ssrc[i];
    const unsigned* p = (const unsigned*)xh + ((size_t)(v & 0x03FFFFFF) << 7);
    accum(v, p[lane], p[64 + lane]);
  }

  int deg = e - s;
  float inv = 1.0f / (float)(deg > 0 ? deg : 1);
  int c2 = lane * 2;
  lds[w][c2]       = (bf16)(xa0 * inv); lds[w][c2 + 1]       = (bf16)(xb0 * inv);
  lds[w][128 + c2] = (bf16)(xa1 * inv); lds[w][128 + c2 + 1] = (bf16)(xb1 * inv);
  lds[w][256 + c2] = (bf16)(xa2 * inv); lds[w][256 + c2 + 1] = (bf16)(xb2 * inv);
  lds[w][384 + c2] = (bf16)(ha0 * inv); lds[w][384 + c2 + 1] = (bf16)(hb0 * inv);
  lds[w][512 + c2] = (bf16)(ha1 * inv); lds[w][512 + c2 + 1] = (bf16)(hb1 * inv);
  lds[w][640 + c2] = (bf16)(ha2 * inv); lds[w][640 + c2 + 1] = (bf16)(hb2 * inv);
  __syncthreads();
  if (act) {
    int t = spos[node];
    int rb = t >> 4, l = t & 15;
    if (lane < 48) {
      size_t unit = (size_t)rb * 1024 + lane * 16 + l;
      ((bf16x8*)Ax)[unit] = *(const bf16x8*)&lds[w][lane * 8];
      ((bf16x8*)Ah)[unit] = *(const bf16x8*)&lds[w][384 + lane * 8];
    }
    if (lane == 63)
      cntf[t] = make_float4(c0 * inv, c1 * inv, (deg - c0 - c1) * inv, (float)deg);
  }
}

__global__ __launch_bounds__(256) void gather_q_kernel(
    const bf16* __restrict__ q, const int* __restrict__ off, const int* __restrict__ ssrc,
    const int* __restrict__ spos, bf16* __restrict__ Aq, int N)
{
  __shared__ alignas(16) bf16 lds[4][384];
  int w = threadIdx.x >> 6, lane = threadIdx.x & 63;
  int node = blockIdx.x * 4 + w;
  bool act = node < N;
  int s = 0, e = 0;
  if (act) { s = off[node]; e = off[node + 1]; }
  float u0a = 0, u0b = 0, u1a = 0, u1b = 0, u2a = 0, u2b = 0;

  auto accum = [&](int v, unsigned aq) {
    int r = ((unsigned)v) >> 26;
    float f0 = bflo_(aq), f1 = bfhi_(aq);
    if (r == 0)      { u0a += f0; u0b += f1; }
    else if (r == 1) { u1a += f0; u1b += f1; }
    else             { u2a += f0; u2b += f1; }
  };

  int i = s;
  for (; i + 4 <= e; i += 4) {
    int v0 = ssrc[i], v1 = ssrc[i + 1], v2 = ssrc[i + 2], v3 = ssrc[i + 3];
    const unsigned* p0 = (const unsigned*)q + ((size_t)(v0 & 0x03FFFFFF) << 6);
    const unsigned* p1 = (const unsigned*)q + ((size_t)(v1 & 0x03FFFFFF) << 6);
    const unsigned* p2 = (const unsigned*)q + ((size_t)(v2 & 0x03FFFFFF) << 6);
    const unsigned* p3 = (const unsigned*)q + ((size_t)(v3 & 0x03FFFFFF) << 6);
    unsigned a0 = p0[lane], a1 = p1[lane], a2 = p2[lane], a3 = p3[lane];
    accum(v0, a0); accum(v1, a1); accum(v2, a2); accum(v3, a3);
  }
  for (; i < e; ++i) {
    int v = ssrc[i];
    accum(v, ((const unsigned*)q + ((size_t)(v & 0x03FFFFFF) << 6))[lane]);
  }

  float inv = 1.0f / (float)(e - s > 0 ? e - s : 1);
  int c2 = lane * 2;
  lds[w][c2]       = (bf16)(u0a * inv); lds[w][c2 + 1]       = (bf16)(u0b * inv);
  lds[w][128 + c2] = (bf16)(u1a * inv); lds[w][128 + c2 + 1] = (bf16)(u1b * inv);
  lds[w][256 + c2] = (bf16)(u2a * inv); lds[w][256 + c2 + 1] = (bf16)(u2b * inv);
  __syncthreads();
  if (act && lane < 48) {
    int t = spos[node];
    size_t unit = (size_t)(t >> 4) * 1024 + lane * 16 + (t & 15);
    ((bf16x8*)Aq)[unit] = *(const bf16x8*)&lds[w][lane * 8];
  }
}

// ---------------- streaming MFMA GEMM (no LDS, no barriers) ----------------
struct GArgs {
  const bf16* wf[3];       // per-conv Wf base (12 kslices)
  const bf16* pf[3];       // per-conv Pf base (3 roles x 2048 units)
  bf16* out[3];            // sorted [t][128]
  const float* bias[3];    // (R,DH) fp32 or null
};

template<int CV, bool HASB>
__global__ __launch_bounds__(256) void gemm_kernel(const bf16* __restrict__ Ap, GArgs ga,
                                                   const float4* __restrict__ cntf,
                                                   const int* __restrict__ roleinfo)
{
  const int bx = blockIdx.x;
  const int w = threadIdx.x >> 6, lane = threadIdx.x & 63;
  const int rb = bx * 4 + w;
  const int s1 = roleinfo[0], s2 = roleinfo[1];
  const int row0 = bx * 64;
  const int role = (row0 >= s2) ? 2 : (row0 >= s1) ? 1 : 0;
  const int q = lane >> 4, l = lane & 15;
  const int laneoff = q * 128 + l;                 // 16B units into B frag block

  f32x4 acc[CV][8];
  #pragma unroll
  for (int cv = 0; cv < CV; ++cv)
    #pragma unroll
    for (int ct = 0; ct < 8; ++ct)
      #pragma unroll
      for (int j = 0; j < 4; ++j) acc[cv][ct][j] = 0.f;

  const bf16x8* Abase = (const bf16x8*)Ap + (size_t)rb * 1024 + lane;

  #pragma unroll
  for (int kslice = 0; kslice < 16; ++kslice) {
    bf16x8 a = Abase[kslice * 64];
    #pragma unroll
    for (int cv = 0; cv < CV; ++cv) {
      const bf16x8* bp = (kslice < 12)
        ? ((const bf16x8*)ga.wf[cv] + kslice * 512 + laneoff)
        : ((const bf16x8*)ga.pf[cv] + role * 2048 + (kslice - 12) * 512 + laneoff);
      #pragma unroll
      for (int ct = 0; ct < 8; ++ct)
        acc[cv][ct] = __builtin_amdgcn_mfma_f32_16x16x32_bf16(a, bp[ct * 16], acc[cv][ct], 0, 0, 0);
    }
  }

  float4 cfs[4];
  if (HASB) {
    #pragma unroll
    for (int reg = 0; reg < 4; ++reg) cfs[reg] = cntf[rb * 16 + q * 4 + reg];
  }
  #pragma unroll
  for (int cv = 0; cv < CV; ++cv) {
    #pragma unroll
    for (int ct = 0; ct < 8; ++ct) {
      int col = ct * 16 + l;
      float b0 = 0, b1 = 0, b2 = 0;
      if (HASB) {
        const float* bb = ga.bias[cv];
        b0 = bb[col]; b1 = bb[128 + col]; b2 = bb[256 + col];
      }
      #pragma unroll
      for (int reg = 0; reg < 4; ++reg) {
        int t = rb * 16 + q * 4 + reg;
        float v = acc[cv][ct][reg];
        if (HASB) v += cfs[reg].x * b0 + cfs[reg].y * b1 + cfs[reg].z * b2;
        ga.out[cv][(size_t)t * 128 + col] = (bf16)fmaxf(v, 0.f);
      }
    }
  }
}

// ---------------- combines (natural order, spos lookup) ----------------
__global__ __launch_bounds__(256) void combine1_kernel(
    const bf16* __restrict__ o0, const bf16* __restrict__ o1,
    const bf16* __restrict__ o2, const bf16* __restrict__ o3,
    const float* __restrict__ h, const int* __restrict__ spos,
    float* __restrict__ zbuf, bf16* __restrict__ qbuf, bf16* __restrict__ Aq, int N)
{
  int g = blockIdx.x * 256 + threadIdx.x;
  if (g >= N * 16) return;
  int n = g >> 4, o = g & 15;
  int t = spos[n];
  size_t tb = ((size_t)t * 128 + o * 8) / 8;
  bf16x8 a0 = ((const bf16x8*)o0)[tb];
  bf16x8 a1 = ((const bf16x8*)o1)[tb];
  bf16x8 a2 = ((const bf16x8*)o2)[tb];
  bf16x8 a3 = ((const bf16x8*)o3)[tb];
  size_t nb = (size_t)n * 16 + o;
  float4 h0 = ((const float4*)h)[nb * 2];
  float4 h1 = ((const float4*)h)[nb * 2 + 1];
  float hv[8] = {h0.x, h0.y, h0.z, h0.w, h1.x, h1.y, h1.z, h1.w};
  float zv[8];
  bf16x8 qv;
  #pragma unroll
  for (int j = 0; j < 8; ++j) {
    zv[j] = sigmoidf_((float)a0[j] + (float)a1[j]);
    qv[j] = (bf16)(sigmoidf_((float)a2[j] + (float)a3[j]) * hv[j]);
  }
  ((float4*)zbuf)[nb * 2]     = make_float4(zv[0], zv[1], zv[2], zv[3]);
  ((float4*)zbuf)[nb * 2 + 1] = make_float4(zv[4], zv[5], zv[6], zv[7]);
  ((bf16x8*)qbuf)[nb] = qv;
  size_t unit = (size_t)(t >> 4) * 1024 + (48 + o) * 16 + (t & 15);
  ((bf16x8*)Aq)[unit] = qv;
}

__global__ __launch_bounds__(256) void combine2_kernel(
    const float* __restrict__ zbuf, const bf16* __restrict__ o4, const bf16* __restrict__ o5,
    const float* __restrict__ h, const int* __restrict__ spos, float* __restrict__ out, int N)
{
  int g = blockIdx.x * 256 + threadIdx.x;
  if (g >= N * 16) return;
  int n = g >> 4, o = g & 15;
  int t = spos[n];
  size_t tb = ((size_t)t * 128 + o * 8) / 8;
  bf16x8 a = ((const bf16x8*)o4)[tb];
  bf16x8 b = ((const bf16x8*)o5)[tb];
  size_t nb = (size_t)n * 16 + o;
  float4 z0 = ((const float4*)zbuf)[nb * 2];
  float4 z1 = ((const float4*)zbuf)[nb * 2 + 1];
  float4 h0 = ((const float4*)h)[nb * 2];
  float4 h1 = ((const float4*)h)[nb * 2 + 1];
  float zv[8] = {z0.x, z0.y, z0.z, z0.w, z1.x, z1.y, z1.z, z1.w};
  float hv[8] = {h0.x, h0.y, h0.z, h0.w, h1.x, h1.y, h1.z, h1.w};
  float ov[8];
  #pragma unroll
  for (int j = 0; j < 8; ++j)
    ov[j] = zv[j] * hv[j] + (1.f - zv[j]) * tanhf((float)a[j] + (float)b[j]);
  ((float4*)out)[nb * 2]     = make_float4(ov[0], ov[1], ov[2], ov[3]);
  ((float4*)out)[nb * 2 + 1] = make_float4(ov[4], ov[5], ov[6], ov[7]);
}

// ---------------- host ----------------
extern "C" void kernel_launch(void* const* d_in, const int* in_sizes, int n_in,
                              void* d_out, int out_size, void* d_ws, size_t ws_size,
                              hipStream_t stream)
{
  (void)n_in; (void)out_size; (void)ws_size;
  const float* x    = (const float*)d_in[0];
  const float* h    = (const float*)d_in[1];
  const int*   ei   = (const int*)d_in[2];
  const int*   role = (const int*)d_in[3];
  const int N = in_sizes[0] / DH;
  const int E = in_sizes[2] / 2;
  const int Etot = E + N;
  const int rows_pad = ((N + 252) + 63) / 64 * 64;
  const int gx = rows_pad / 64;

  // conv order: 0 xz, 1 hz, 2 xr, 3 hr, 4 xh, 5 hh
  static const int Wi[6]  = {4, 9, 13, 18, 22, 27};
  static const int Wgi[6] = {5, 10, 14, 19, 23, 28};
  static const int bgi[6] = {6, 11, 15, 20, 24, 29};
  static const int Si[6]  = {7, 12, 16, 21, 25, 30};
  static const int bi[6]  = {8, -1, 17, -1, 26, -1};

  char* p = (char*)d_ws;
  auto alloc = [&](size_t bytes) -> char* {
    char* r = p;
    p += (bytes + 255) & ~(size_t)255;
    return r;
  };

  bf16* Ax = (bf16*)alloc((size_t)rows_pad * 512 * 2);   // Aq aliases Ax
  bf16* Ah = (bf16*)alloc((size_t)rows_pad * 512 * 2);
  bf16* Aq = Ax;
  bf16* xh = (bf16*)alloc((size_t)N * 256 * 2);
  bf16* outs[6];
  for (int c = 0; c < 5; ++c) outs[c] = (bf16*)alloc((size_t)rows_pad * 128 * 2);
  outs[5] = outs[0];                                     // alias, free after combine1
  float* zbuf = (float*)alloc((size_t)N * 128 * 4);
  bf16* qbuf  = (bf16*)alloc((size_t)N * 128 * 2);
  float4* cntf = (float4*)alloc((size_t)rows_pad * 16);
  bf16* Wf = (bf16*)alloc((size_t)6 * 49152 * 2);
  bf16* Pf = (bf16*)alloc((size_t)18 * 16384 * 2);
  int* cnt   = (int*)alloc((size_t)N * 4);
  int* off   = (int*)alloc((size_t)(N + 1) * 4);
  int* fill  = (int*)alloc((size_t)N * 4);
  int* ssrc  = (int*)alloc((size_t)Etot * 4);
  int* spos  = (int*)alloc((size_t)N * 4);
  int* rolecnt  = (int*)alloc(64);
  int* rolefill = (int*)alloc(64);
  int* roleinfo = (int*)alloc(64);

  hipMemsetAsync(cnt, 0, (size_t)N * 4, stream);
  hipMemsetAsync(rolecnt, 0, 16, stream);

  int egrid = (Etot + 255) / 256;
  int ngrid = (N + 255) / 256;
  hist_kernel<<<egrid, 256, 0, stream>>>(ei, cnt, E, N);
  rolehist_kernel<<<ngrid, 256, 0, stream>>>(role, rolecnt, N);
  scan_kernel<<<1, 1024, 0, stream>>>(cnt, off, fill, N);
  roleoff_kernel<<<1, 1, 0, stream>>>(rolecnt, rolefill, roleinfo);
  scatter_kernel<<<egrid, 256, 0, stream>>>(ei, role, fill, ssrc, E, N);
  permscatter_kernel<<<ngrid, 256, 0, stream>>>(role, rolefill, spos, N);
  zeropad_kernel<<<96, 256, 0, stream>>>(roleinfo, Ax, Ah);

  prep_xh_kernel<<<(N * 32 + 255) / 256, 256, 0, stream>>>(x, h, spos, xh, Ax, Ah, N);

  PrepW pw;
  for (int c = 0; c < 6; ++c) {
    pw.W[c] = (const float*)d_in[Wi[c]];
    pw.Wg[c] = (const float*)d_in[Wgi[c]];
    pw.bg[c] = (const float*)d_in[bgi[c]];
  }
  prep_wf_kernel<<<1152, 256, 0, stream>>>(pw, Wf);
  PrepP pp;
  for (int c = 0; c < 6; ++c) { pp.W[c] = (const float*)d_in[Wi[c]]; pp.S[c] = (const float*)d_in[Si[c]]; }
  prep_pf_kernel<<<2304, 128, 0, stream>>>(pp, Pf);

  gather_xh_kernel<<<(N + 3) / 4, 256, 0, stream>>>(xh, off, ssrc, spos, Ax, Ah, cntf, N);

  // y0: convs {xz(0), xr(2), xh(4)} on A'x = [Ux|x], with bias
  GArgs g0;
  { int cvs[3] = {0, 2, 4};
    for (int k = 0; k < 3; ++k) {
      int c = cvs[k];
      g0.wf[k] = Wf + (size_t)c * 49152;
      g0.pf[k] = Pf + (size_t)c * 3 * 16384;
      g0.out[k] = outs[c];
      g0.bias[k] = (const float*)d_in[bi[c]];
    } }
  gemm_kernel<3, true><<<gx, 256, 0, stream>>>(Ax, g0, cntf, roleinfo);

  // y1: convs {hz(1), hr(3)} on A'h = [Uh|h], no bias
  GArgs g1 = {};
  { int cvs[2] = {1, 3};
    for (int k = 0; k < 2; ++k) {
      int c = cvs[k];
      g1.wf[k] = Wf + (size_t)c * 49152;
      g1.pf[k] = Pf + (size_t)c * 3 * 16384;
      g1.out[k] = outs[c];
      g1.bias[k] = nullptr;
    } }
  gemm_kernel<2, false><<<gx, 256, 0, stream>>>(Ah, g1, cntf, roleinfo);

  combine1_kernel<<<(N * 16 + 255) / 256, 256, 0, stream>>>(outs[0], outs[1], outs[2], outs[3],
                                                            h, spos, zbuf, qbuf, Aq, N);

  gather_q_kernel<<<(N + 3) / 4, 256, 0, stream>>>(qbuf, off, ssrc, spos, Aq, N);

  // pass2: conv hh(5) on A'q = [Uq|q], no bias
  GArgs g2 = {};
  g2.wf[0] = Wf + (size_t)5 * 49152;
  g2.pf[0] = Pf + (size_t)5 * 3 * 16384;
  g2.out[0] = outs[5];
  g2.bias[0] = nullptr;
  gemm_kernel<1, false><<<gx, 256, 0, stream>>>(Aq, g2, cntf, roleinfo);

  combine2_kernel<<<(N * 16 + 255) / 256, 256, 0, stream>>>(zbuf, outs[4], outs[5], h, spos,
                                                            (float*)d_out, N);
}

// Round 4
// 907.725 us; speedup vs baseline: 1.3032x; 1.0726x over previous
//
#include <hip/hip_runtime.h>

// GraphGRU on MI355X — round 4.
//   gather_xh: ONE dwordx2 load per edge (lanes 0-31 = x cols, 32-63 = h cols).
//   gemm: streaming barrier-free MFMA, each wave owns 4 row-blocks (64 rows) and
//   reuses every B fragment 4x; role regions 256-aligned so role is block-uniform;
//   all 5 pass-1 convs in one dispatch (grid gx x 5).

typedef __bf16 bf16;
typedef __bf16 bf16x4 __attribute__((ext_vector_type(4)));
typedef __bf16 bf16x8 __attribute__((ext_vector_type(8)));
typedef float  f32x4  __attribute__((ext_vector_type(4)));

#define DH 128

__device__ __forceinline__ float sigmoidf_(float x) { return 1.0f / (1.0f + expf(-x)); }
__device__ __forceinline__ float bflo_(unsigned u) { return __uint_as_float(u << 16); }
__device__ __forceinline__ float bfhi_(unsigned u) { return __uint_as_float(u & 0xffff0000u); }

// ---------------- CSR build ----------------
__global__ __launch_bounds__(256) void hist_kernel(const int* __restrict__ ei, int* __restrict__ cnt,
                                                   int E, int N)
{
  int i = blockIdx.x * 256 + threadIdx.x;
  if (i < E + N) {
    int c = (i < E) ? ei[E + i] : (i - E);
    atomicAdd(&cnt[c], 1);
  }
}

__global__ __launch_bounds__(1024) void scan_kernel(const int* __restrict__ cnt, int* __restrict__ off,
                                                    int* __restrict__ fill, int n)
{
  __shared__ int wsum[17];
  int t = threadIdx.x, lane = t & 63, w = t >> 6;
  if (t == 0) { wsum[16] = 0; off[0] = 0; fill[0] = 0; }
  __syncthreads();
  for (int base = 0; base < n; base += 1024) {
    int carry = wsum[16];
    int idx = base + t;
    int v = (idx < n) ? cnt[idx] : 0;
    int s = v;
    #pragma unroll
    for (int d = 1; d < 64; d <<= 1) { int u = __shfl_up(s, d); if (lane >= d) s += u; }
    if (lane == 63) wsum[w] = s;
    __syncthreads();
    if (w == 0 && lane < 16) {
      int ws = wsum[lane];
      #pragma unroll
      for (int d = 1; d < 16; d <<= 1) { int u = __shfl_up(ws, d); if (lane >= d) ws += u; }
      wsum[lane] = ws;
    }
    __syncthreads();
    int inc = carry + ((w > 0) ? wsum[w - 1] : 0) + s;
    if (idx < n) {
      off[idx + 1] = inc;
      if (idx + 1 < n) fill[idx + 1] = inc;
    }
    __syncthreads();
    if (t == 0) wsum[16] = carry + wsum[15];
    __syncthreads();
  }
}

// ssrc packs src | role(src)<<26
__global__ __launch_bounds__(256) void scatter_kernel(const int* __restrict__ ei, const int* __restrict__ role,
                                                      int* __restrict__ fill, int* __restrict__ ssrc, int E, int N)
{
  int i = blockIdx.x * 256 + threadIdx.x;
  if (i < E + N) {
    int c, r;
    if (i < E) { c = ei[E + i]; r = ei[i]; } else { c = i - E; r = i - E; }
    int pz = atomicAdd(&fill[c], 1);
    ssrc[pz] = r | (role[r] << 26);
  }
}

// ---------------- role sort ----------------
__global__ __launch_bounds__(256) void rolehist_kernel(const int* __restrict__ role, int* __restrict__ rolecnt, int N)
{
  int i = blockIdx.x * 256 + threadIdx.x;
  int lane = threadIdx.x & 63;
  int r = (i < N) ? role[i] : -1;
  #pragma unroll
  for (int rr = 0; rr < 3; ++rr) {
    unsigned long long mask = __ballot(r == rr);
    if (lane == 0 && mask) atomicAdd(&rolecnt[rr], __popcll(mask));
  }
}

// roleinfo: {s1, s2, g0s, g0l, g1s, g1l, g2s, g2l}; rolefill: {0, s1, s2}
// 256-row alignment so 256-row GEMM blocks are role-uniform.
__global__ void roleoff_kernel(const int* __restrict__ rolecnt, int* __restrict__ rolefill,
                               int* __restrict__ roleinfo)
{
  int c0 = rolecnt[0], c1 = rolecnt[1], c2 = rolecnt[2];
  int s1 = (c0 + 255) & ~255;
  int s2 = s1 + ((c1 + 255) & ~255);
  int mp = s2 + ((c2 + 255) & ~255);
  rolefill[0] = 0; rolefill[1] = s1; rolefill[2] = s2;
  roleinfo[0] = s1; roleinfo[1] = s2;
  roleinfo[2] = c0;      roleinfo[3] = s1 - c0;
  roleinfo[4] = s1 + c1; roleinfo[5] = s2 - s1 - c1;
  roleinfo[6] = s2 + c2; roleinfo[7] = mp - s2 - c2;
}

__global__ __launch_bounds__(256) void permscatter_kernel(const int* __restrict__ role, int* __restrict__ rolefill,
                                                          int* __restrict__ spos, int N)
{
  int i = blockIdx.x * 256 + threadIdx.x;
  int lane = threadIdx.x & 63;
  int r = (i < N) ? role[i] : -1;
  #pragma unroll
  for (int rr = 0; rr < 3; ++rr) {
    unsigned long long mask = __ballot(r == rr);
    if (!mask) continue;
    int base = 0;
    if (lane == 0) base = atomicAdd(&rolefill[rr], __popcll(mask));
    base = __shfl(base, 0);
    if (r == rr) {
      int rank = (int)__popcll(mask & ((1ull << lane) - 1ull));
      spos[i] = base + rank;
    }
  }
}

// zero pad rows of Ax, Ah (gaps up to 255 rows). 2 arrays x 3 gaps x 256 rows x 64 chunks.
__global__ __launch_bounds__(256) void zeropad_kernel(const int* __restrict__ roleinfo,
                                                      bf16* __restrict__ Ax, bf16* __restrict__ Ah)
{
  int id = blockIdx.x * 256 + threadIdx.x;   // 98304
  int a = id / 49152, rem = id % 49152;
  int gp = rem / 16384, r2 = rem % 16384;
  int rr = r2 >> 6, c = r2 & 63;
  int gs = roleinfo[2 + gp * 2], gl = roleinfo[3 + gp * 2];
  if (rr < gl) {
    int row = gs + rr;
    size_t unit = (size_t)(row >> 4) * 1024 + c * 16 + (row & 15);
    bf16x8 z = {};
    ((bf16x8*)(a == 0 ? Ax : Ah))[unit] = z;
  }
}

// ---------------- prep ----------------
__global__ __launch_bounds__(256) void prep_xh_kernel(const float* __restrict__ x, const float* __restrict__ h,
                                                      const int* __restrict__ spos, bf16* __restrict__ xh,
                                                      bf16* __restrict__ Ax, bf16* __restrict__ Ah, int N)
{
  int g = blockIdx.x * 256 + threadIdx.x;
  if (g >= N * 32) return;
  int n = g >> 5, j = g & 31;
  int t = spos[n];
  int rb = t >> 4, l = t & 15;
  const float* src = (j < 16) ? (x + (size_t)n * 128 + j * 8) : (h + (size_t)n * 128 + (j - 16) * 8);
  float4 v0 = ((const float4*)src)[0];
  float4 v1 = ((const float4*)src)[1];
  bf16x8 o;
  o[0] = (bf16)v0.x; o[1] = (bf16)v0.y; o[2] = (bf16)v0.z; o[3] = (bf16)v0.w;
  o[4] = (bf16)v1.x; o[5] = (bf16)v1.y; o[6] = (bf16)v1.z; o[7] = (bf16)v1.w;
  int j16 = j & 15;
  ((bf16x8*)xh)[(size_t)n * 32 + j] = o;
  size_t unit = (size_t)rb * 1024 + (48 + j16) * 16 + l;
  ((bf16x8*)(j < 16 ? Ax : Ah))[unit] = o;
}

struct PrepW { const float* W[6]; const float* Wg[6]; const float* bg[6]; };
__global__ __launch_bounds__(256) void prep_wf_kernel(PrepW pw, bf16* __restrict__ Wf)
{
  int idx = blockIdx.x * 256 + threadIdx.x;
  if (idx >= 294912) return;
  int cv = idx / 49152, pos = idx % 49152;
  int ks4q = pos >> 10;
  int col = (pos >> 3) & 127, j = pos & 7;
  int k = (ks4q >> 2) * 32 + (ks4q & 3) * 8 + j;
  int r = k >> 7, kk = k & 127;
  float g = sigmoidf_(pw.Wg[cv][r * 128 + col] + pw.bg[cv][r * 128 + col]);
  Wf[idx] = (bf16)(pw.W[cv][kk * 128 + col] * g);
}

struct PrepP { const float* W[6]; const float* S[6]; };
__global__ __launch_bounds__(128) void prep_pf_kernel(PrepP pp, bf16* __restrict__ Pf)
{
  int b = blockIdx.x;                          // 6*3*128
  int cv = b / 384, rem = b % 384;
  int r = rem >> 7, kp = rem & 127;
  int col = threadIdx.x;
  const float* W = pp.W[cv] + (size_t)kp * 128;
  const float* S = pp.S[cv] + (size_t)r * 16384;
  float sum = 0.f;
  #pragma unroll 4
  for (int j2 = 0; j2 < 128; ++j2) sum += W[j2] * S[j2 * 128 + col];
  size_t o = (size_t)(cv * 3 + r) * 16384 + ((size_t)(kp >> 3) * 128 + col) * 8 + (kp & 7);
  Pf[o] = (bf16)sum;
}

// ---------------- gathers ----------------
// ONE 8B load per edge: lane covers bf16 cols lane*4..lane*4+3 of the 256-wide x|h row.
__global__ __launch_bounds__(256) void gather_xh_kernel(
    const bf16* __restrict__ xh, const int* __restrict__ off, const int* __restrict__ ssrc,
    const int* __restrict__ spos, bf16* __restrict__ Ax, bf16* __restrict__ Ah,
    float4* __restrict__ cntf, int N)
{
  __shared__ alignas(16) bf16 lds[4][768];
  int w = threadIdx.x >> 6, lane = threadIdx.x & 63;
  int node = blockIdx.x * 4 + w;
  bool act = node < N;
  int s = 0, e = 0;
  if (act) { s = off[node]; e = off[node + 1]; }
  float u0[4] = {0, 0, 0, 0}, u1[4] = {0, 0, 0, 0}, u2[4] = {0, 0, 0, 0};
  int c0 = 0, c1 = 0;

  auto accum = [&](int v, bf16x4 row) {
    int r = ((unsigned)v) >> 26;
    float f0 = (float)row[0], f1 = (float)row[1], f2 = (float)row[2], f3 = (float)row[3];
    if (r == 0)      { u0[0] += f0; u0[1] += f1; u0[2] += f2; u0[3] += f3; c0++; }
    else if (r == 1) { u1[0] += f0; u1[1] += f1; u1[2] += f2; u1[3] += f3; c1++; }
    else             { u2[0] += f0; u2[1] += f1; u2[2] += f2; u2[3] += f3; }
  };

  int i = s;
  for (; i + 4 <= e; i += 4) {
    int v0 = ssrc[i], v1 = ssrc[i + 1], v2 = ssrc[i + 2], v3 = ssrc[i + 3];
    bf16x4 r0 = *(const bf16x4*)(xh + ((size_t)(v0 & 0x03FFFFFF) << 8) + lane * 4);
    bf16x4 r1 = *(const bf16x4*)(xh + ((size_t)(v1 & 0x03FFFFFF) << 8) + lane * 4);
    bf16x4 r2 = *(const bf16x4*)(xh + ((size_t)(v2 & 0x03FFFFFF) << 8) + lane * 4);
    bf16x4 r3 = *(const bf16x4*)(xh + ((size_t)(v3 & 0x03FFFFFF) << 8) + lane * 4);
    accum(v0, r0); accum(v1, r1); accum(v2, r2); accum(v3, r3);
  }
  for (; i < e; ++i) {
    int v = ssrc[i];
    bf16x4 rr = *(const bf16x4*)(xh + ((size_t)(v & 0x03FFFFFF) << 8) + lane * 4);
    accum(v, rr);
  }

  int deg = e - s;
  float inv = 1.0f / (float)(deg > 0 ? deg : 1);
  int sec = (lane < 32) ? 0 : 384;
  int cid = (lane & 31) * 4;
  bf16x4 o;
  o[0] = (bf16)(u0[0] * inv); o[1] = (bf16)(u0[1] * inv); o[2] = (bf16)(u0[2] * inv); o[3] = (bf16)(u0[3] * inv);
  *(bf16x4*)&lds[w][sec + cid] = o;
  o[0] = (bf16)(u1[0] * inv); o[1] = (bf16)(u1[1] * inv); o[2] = (bf16)(u1[2] * inv); o[3] = (bf16)(u1[3] * inv);
  *(bf16x4*)&lds[w][sec + 128 + cid] = o;
  o[0] = (bf16)(u2[0] * inv); o[1] = (bf16)(u2[1] * inv); o[2] = (bf16)(u2[2] * inv); o[3] = (bf16)(u2[3] * inv);
  *(bf16x4*)&lds[w][sec + 256 + cid] = o;
  __syncthreads();
  if (act) {
    int t = spos[node];
    int rb = t >> 4, l16 = t & 15;
    if (lane < 48) {
      size_t unit = (size_t)rb * 1024 + lane * 16 + l16;
      ((bf16x8*)Ax)[unit] = *(const bf16x8*)&lds[w][lane * 8];
      ((bf16x8*)Ah)[unit] = *(const bf16x8*)&lds[w][384 + lane * 8];
    }
    if (lane == 63)
      cntf[t] = make_float4(c0 * inv, c1 * inv, (deg - c0 - c1) * inv, (float)deg);
  }
}

__global__ __launch_bounds__(256) void gather_q_kernel(
    const bf16* __restrict__ q, const int* __restrict__ off, const int* __restrict__ ssrc,
    const int* __restrict__ spos, bf16* __restrict__ Aq, int N)
{
  __shared__ alignas(16) bf16 lds[4][384];
  int w = threadIdx.x >> 6, lane = threadIdx.x & 63;
  int node = blockIdx.x * 4 + w;
  bool act = node < N;
  int s = 0, e = 0;
  if (act) { s = off[node]; e = off[node + 1]; }
  float u0a = 0, u0b = 0, u1a = 0, u1b = 0, u2a = 0, u2b = 0;

  auto accum = [&](int v, unsigned aq) {
    int r = ((unsigned)v) >> 26;
    float f0 = bflo_(aq), f1 = bfhi_(aq);
    if (r == 0)      { u0a += f0; u0b += f1; }
    else if (r == 1) { u1a += f0; u1b += f1; }
    else             { u2a += f0; u2b += f1; }
  };

  int i = s;
  for (; i + 4 <= e; i += 4) {
    int v0 = ssrc[i], v1 = ssrc[i + 1], v2 = ssrc[i + 2], v3 = ssrc[i + 3];
    unsigned a0 = ((const unsigned*)q)[((size_t)(v0 & 0x03FFFFFF) << 6) + lane];
    unsigned a1 = ((const unsigned*)q)[((size_t)(v1 & 0x03FFFFFF) << 6) + lane];
    unsigned a2 = ((const unsigned*)q)[((size_t)(v2 & 0x03FFFFFF) << 6) + lane];
    unsigned a3 = ((const unsigned*)q)[((size_t)(v3 & 0x03FFFFFF) << 6) + lane];
    accum(v0, a0); accum(v1, a1); accum(v2, a2); accum(v3, a3);
  }
  for (; i < e; ++i) {
    int v = ssrc[i];
    accum(v, ((const unsigned*)q)[((size_t)(v & 0x03FFFFFF) << 6) + lane]);
  }

  float inv = 1.0f / (float)(e - s > 0 ? e - s : 1);
  int c2 = lane * 2;
  lds[w][c2]       = (bf16)(u0a * inv); lds[w][c2 + 1]       = (bf16)(u0b * inv);
  lds[w][128 + c2] = (bf16)(u1a * inv); lds[w][128 + c2 + 1] = (bf16)(u1b * inv);
  lds[w][256 + c2] = (bf16)(u2a * inv); lds[w][256 + c2 + 1] = (bf16)(u2b * inv);
  __syncthreads();
  if (act && lane < 48) {
    int t = spos[node];
    size_t unit = (size_t)(t >> 4) * 1024 + lane * 16 + (t & 15);
    ((bf16x8*)Aq)[unit] = *(const bf16x8*)&lds[w][lane * 8];
  }
}

// ---------------- streaming MFMA GEMM (no LDS/barriers; 4 row-blocks per wave) ----------------
struct GArgs {
  const bf16* Ap[5];
  const bf16* wf[5];
  const bf16* pf[5];
  bf16* out[5];
  const float* bias[5];
};

__global__ __launch_bounds__(256) void gemm_kernel(GArgs ga, const float4* __restrict__ cntf,
                                                   const int* __restrict__ roleinfo)
{
  const int cv = blockIdx.y;
  const bf16* __restrict__ Ap = ga.Ap[cv];
  const bf16* __restrict__ wf = ga.wf[cv];
  const bf16* __restrict__ pf = ga.pf[cv];
  bf16* __restrict__ out = ga.out[cv];
  const float* __restrict__ bias = ga.bias[cv];

  const int w = threadIdx.x >> 6, lane = threadIdx.x & 63;
  const int q = lane >> 4, l = lane & 15;
  const int rb0 = blockIdx.x * 16 + w * 4;
  const int row0 = blockIdx.x * 256;
  const int s1 = roleinfo[0], s2 = roleinfo[1];
  const int role = (row0 >= s2) ? 2 : (row0 >= s1) ? 1 : 0;
  const int laneoff = q * 128 + l;

  f32x4 acc[4][8];
  #pragma unroll
  for (int j = 0; j < 4; ++j)
    #pragma unroll
    for (int ct = 0; ct < 8; ++ct)
      #pragma unroll
      for (int k = 0; k < 4; ++k) acc[j][ct][k] = 0.f;

  const bf16x8* A0 = (const bf16x8*)Ap + (size_t)rb0 * 1024 + lane;
  const bf16x8* WF = (const bf16x8*)wf + laneoff;
  const bf16x8* PF = (const bf16x8*)pf + role * 2048 + laneoff;

  #pragma unroll 2
  for (int ks = 0; ks < 16; ++ks) {
    const bf16x8* bp = (ks < 12) ? (WF + ks * 512) : (PF + (ks - 12) * 512);
    bf16x8 a0 = A0[ks * 64];
    bf16x8 a1 = A0[1024 + ks * 64];
    bf16x8 a2 = A0[2048 + ks * 64];
    bf16x8 a3 = A0[3072 + ks * 64];
    #pragma unroll
    for (int ct = 0; ct < 8; ++ct) {
      bf16x8 b = bp[ct * 16];
      acc[0][ct] = __builtin_amdgcn_mfma_f32_16x16x32_bf16(a0, b, acc[0][ct], 0, 0, 0);
      acc[1][ct] = __builtin_amdgcn_mfma_f32_16x16x32_bf16(a1, b, acc[1][ct], 0, 0, 0);
      acc[2][ct] = __builtin_amdgcn_mfma_f32_16x16x32_bf16(a2, b, acc[2][ct], 0, 0, 0);
      acc[3][ct] = __builtin_amdgcn_mfma_f32_16x16x32_bf16(a3, b, acc[3][ct], 0, 0, 0);
    }
  }

  const bool hb = (bias != nullptr);
  #pragma unroll
  for (int j = 0; j < 4; ++j) {
    int rb = rb0 + j;
    float4 cfs[4];
    if (hb) {
      #pragma unroll
      for (int reg = 0; reg < 4; ++reg) cfs[reg] = cntf[rb * 16 + q * 4 + reg];
    }
    #pragma unroll
    for (int ct = 0; ct < 8; ++ct) {
      int col = ct * 16 + l;
      float b0 = 0, b1 = 0, b2 = 0;
      if (hb) { b0 = bias[col]; b1 = bias[128 + col]; b2 = bias[256 + col]; }
      #pragma unroll
      for (int reg = 0; reg < 4; ++reg) {
        int t = rb * 16 + q * 4 + reg;
        float v = acc[j][ct][reg];
        if (hb) v += cfs[reg].x * b0 + cfs[reg].y * b1 + cfs[reg].z * b2;
        out[(size_t)t * 128 + col] = (bf16)fmaxf(v, 0.f);
      }
    }
  }
}

// ---------------- combines ----------------
__global__ __launch_bounds__(256) void combine1_kernel(
    const bf16* __restrict__ o0, const bf16* __restrict__ o1,
    const bf16* __restrict__ o2, const bf16* __restrict__ o3,
    const float* __restrict__ h, const int* __restrict__ spos,
    float* __restrict__ zbuf, bf16* __restrict__ qbuf, bf16* __restrict__ Aq, int N)
{
  int g = blockIdx.x * 256 + threadIdx.x;
  if (g >= N * 16) return;
  int n = g >> 4, o = g & 15;
  int t = spos[n];
  size_t tb = ((size_t)t * 128 + o * 8) / 8;
  bf16x8 a0 = ((const bf16x8*)o0)[tb];
  bf16x8 a1 = ((const bf16x8*)o1)[tb];
  bf16x8 a2 = ((const bf16x8*)o2)[tb];
  bf16x8 a3 = ((const bf16x8*)o3)[tb];
  size_t nb = (size_t)n * 16 + o;
  float4 h0 = ((const float4*)h)[nb * 2];
  float4 h1 = ((const float4*)h)[nb * 2 + 1];
  float hv[8] = {h0.x, h0.y, h0.z, h0.w, h1.x, h1.y, h1.z, h1.w};
  float zv[8];
  bf16x8 qv;
  #pragma unroll
  for (int j = 0; j < 8; ++j) {
    zv[j] = sigmoidf_((float)a0[j] + (float)a1[j]);
    qv[j] = (bf16)(sigmoidf_((float)a2[j] + (float)a3[j]) * hv[j]);
  }
  ((float4*)zbuf)[nb * 2]     = make_float4(zv[0], zv[1], zv[2], zv[3]);
  ((float4*)zbuf)[nb * 2 + 1] = make_float4(zv[4], zv[5], zv[6], zv[7]);
  ((bf16x8*)qbuf)[nb] = qv;
  size_t unit = (size_t)(t >> 4) * 1024 + (48 + o) * 16 + (t & 15);
  ((bf16x8*)Aq)[unit] = qv;
}

__global__ __launch_bounds__(256) void combine2_kernel(
    const float* __restrict__ zbuf, const bf16* __restrict__ o4, const bf16* __restrict__ o5,
    const float* __restrict__ h, const int* __restrict__ spos, float* __restrict__ out, int N)
{
  int g = blockIdx.x * 256 + threadIdx.x;
  if (g >= N * 16) return;
  int n = g >> 4, o = g & 15;
  int t = spos[n];
  size_t tb = ((size_t)t * 128 + o * 8) / 8;
  bf16x8 a = ((const bf16x8*)o4)[tb];
  bf16x8 b = ((const bf16x8*)o5)[tb];
  size_t nb = (size_t)n * 16 + o;
  float4 z0 = ((const float4*)zbuf)[nb * 2];
  float4 z1 = ((const float4*)zbuf)[nb * 2 + 1];
  float4 h0 = ((const float4*)h)[nb * 2];
  float4 h1 = ((const float4*)h)[nb * 2 + 1];
  float zv[8] = {z0.x, z0.y, z0.z, z0.w, z1.x, z1.y, z1.z, z1.w};
  float hv[8] = {h0.x, h0.y, h0.z, h0.w, h1.x, h1.y, h1.z, h1.w};
  float ov[8];
  #pragma unroll
  for (int j = 0; j < 8; ++j)
    ov[j] = zv[j] * hv[j] + (1.f - zv[j]) * tanhf((float)a[j] + (float)b[j]);
  ((float4*)out)[nb * 2]     = make_float4(ov[0], ov[1], ov[2], ov[3]);
  ((float4*)out)[nb * 2 + 1] = make_float4(ov[4], ov[5], ov[6], ov[7]);
}

// ---------------- host ----------------
extern "C" void kernel_launch(void* const* d_in, const int* in_sizes, int n_in,
                              void* d_out, int out_size, void* d_ws, size_t ws_size,
                              hipStream_t stream)
{
  (void)n_in; (void)out_size; (void)ws_size;
  const float* x    = (const float*)d_in[0];
  const float* h    = (const float*)d_in[1];
  const int*   ei   = (const int*)d_in[2];
  const int*   role = (const int*)d_in[3];
  const int N = in_sizes[0] / DH;
  const int E = in_sizes[2] / 2;
  const int Etot = E + N;
  const int rows_pad = ((N + 765) + 255) & ~255;    // covers 3x 256-aligned role regions
  const int gx = rows_pad / 256;

  // conv order: 0 xz, 1 hz, 2 xr, 3 hr, 4 xh, 5 hh
  static const int Wi[6]  = {4, 9, 13, 18, 22, 27};
  static const int Wgi[6] = {5, 10, 14, 19, 23, 28};
  static const int bgi[6] = {6, 11, 15, 20, 24, 29};
  static const int Si[6]  = {7, 12, 16, 21, 25, 30};

  char* p = (char*)d_ws;
  auto alloc = [&](size_t bytes) -> char* {
    char* r = p;
    p += (bytes + 255) & ~(size_t)255;
    return r;
  };

  bf16* Ax = (bf16*)alloc((size_t)rows_pad * 512 * 2);   // Aq aliases Ax
  bf16* Ah = (bf16*)alloc((size_t)rows_pad * 512 * 2);
  bf16* Aq = Ax;
  bf16* xh = (bf16*)alloc((size_t)N * 256 * 2);
  bf16* outs[6];
  for (int c = 0; c < 5; ++c) outs[c] = (bf16*)alloc((size_t)rows_pad * 128 * 2);
  outs[5] = outs[0];
  float* zbuf = (float*)alloc((size_t)N * 128 * 4);
  bf16* qbuf  = (bf16*)alloc((size_t)N * 128 * 2);
  float4* cntf = (float4*)alloc((size_t)rows_pad * 16);
  bf16* Wf = (bf16*)alloc((size_t)6 * 49152 * 2);
  bf16* Pf = (bf16*)alloc((size_t)18 * 16384 * 2);
  int* cnt   = (int*)alloc((size_t)N * 4);
  int* off   = (int*)alloc((size_t)(N + 1) * 4);
  int* fill  = (int*)alloc((size_t)N * 4);
  int* ssrc  = (int*)alloc((size_t)Etot * 4);
  int* spos  = (int*)alloc((size_t)N * 4);
  int* rolecnt  = (int*)alloc(64);
  int* rolefill = (int*)alloc(64);
  int* roleinfo = (int*)alloc(64);

  hipMemsetAsync(cnt, 0, (size_t)N * 4, stream);
  hipMemsetAsync(rolecnt, 0, 16, stream);

  int egrid = (Etot + 255) / 256;
  int ngrid = (N + 255) / 256;
  hist_kernel<<<egrid, 256, 0, stream>>>(ei, cnt, E, N);
  rolehist_kernel<<<ngrid, 256, 0, stream>>>(role, rolecnt, N);
  scan_kernel<<<1, 1024, 0, stream>>>(cnt, off, fill, N);
  roleoff_kernel<<<1, 1, 0, stream>>>(rolecnt, rolefill, roleinfo);
  scatter_kernel<<<egrid, 256, 0, stream>>>(ei, role, fill, ssrc, E, N);
  permscatter_kernel<<<ngrid, 256, 0, stream>>>(role, rolefill, spos, N);
  zeropad_kernel<<<384, 256, 0, stream>>>(roleinfo, Ax, Ah);

  prep_xh_kernel<<<(N * 32 + 255) / 256, 256, 0, stream>>>(x, h, spos, xh, Ax, Ah, N);

  PrepW pw;
  for (int c = 0; c < 6; ++c) {
    pw.W[c] = (const float*)d_in[Wi[c]];
    pw.Wg[c] = (const float*)d_in[Wgi[c]];
    pw.bg[c] = (const float*)d_in[bgi[c]];
  }
  prep_wf_kernel<<<1152, 256, 0, stream>>>(pw, Wf);
  PrepP pp;
  for (int c = 0; c < 6; ++c) { pp.W[c] = (const float*)d_in[Wi[c]]; pp.S[c] = (const float*)d_in[Si[c]]; }
  prep_pf_kernel<<<2304, 128, 0, stream>>>(pp, Pf);

  gather_xh_kernel<<<(N + 3) / 4, 256, 0, stream>>>(xh, off, ssrc, spos, Ax, Ah, cntf, N);

  // pass 1: one dispatch, cv 0..4 = {xz,xr,xh on Ax (bias)} + {hz,hr on Ah}
  GArgs g0;
  { int cvs[5] = {0, 2, 4, 1, 3};
    static const int bi2[5] = {8, 17, 26, -1, -1};
    const bf16* Apts[5] = {Ax, Ax, Ax, Ah, Ah};
    for (int k = 0; k < 5; ++k) {
      int c = cvs[k];
      g0.Ap[k] = Apts[k];
      g0.wf[k] = Wf + (size_t)c * 49152;
      g0.pf[k] = Pf + (size_t)c * 3 * 16384;
      g0.out[k] = outs[c];
      g0.bias[k] = (bi2[k] >= 0) ? (const float*)d_in[bi2[k]] : nullptr;
    } }
  gemm_kernel<<<dim3(gx, 5), 256, 0, stream>>>(g0, cntf, roleinfo);

  combine1_kernel<<<(N * 16 + 255) / 256, 256, 0, stream>>>(outs[0], outs[1], outs[2], outs[3],
                                                            h, spos, zbuf, qbuf, Aq, N);

  gather_q_kernel<<<(N + 3) / 4, 256, 0, stream>>>(qbuf, off, ssrc, spos, Aq, N);

  // pass 2: conv hh(5) on Aq
  GArgs g2 = {};
  g2.Ap[0] = Aq;
  g2.wf[0] = Wf + (size_t)5 * 49152;
  g2.pf[0] = Pf + (size_t)5 * 3 * 16384;
  g2.out[0] = outs[5];
  g2.bias[0] = nullptr;
  gemm_kernel<<<dim3(gx, 1), 256, 0, stream>>>(g2, cntf, roleinfo);

  combine2_kernel<<<(N * 16 + 255) / 256, 256, 0, stream>>>(zbuf, outs[4], outs[5], h, spos,
                                                            (float*)d_out, N);
}

// Round 5
// 782.564 us; speedup vs baseline: 1.5116x; 1.1599x over previous
//
#include <hip/hip_runtime.h>

// GraphGRU on MI355X — round 5.
//   Gathers read fp8(e4m3) neighbor rows (halved bytes/edge; self path stays bf16),
//   stored role-sorted so role(src) = two scalar compares on ssrc value (= spos[src]).
//   Hierarchical 3-kernel scan replaces the single-block serial scan.
//   GEMM unchanged from round 4 (streaming barrier-free MFMA, 4 row-blocks/wave).

typedef __bf16 bf16;
typedef __bf16 bf16x8 __attribute__((ext_vector_type(8)));
typedef float  f32x4  __attribute__((ext_vector_type(4)));
typedef float  f32x2  __attribute__((ext_vector_type(2)));
typedef unsigned char u8;

#define DH 128

__device__ __forceinline__ float sigmoidf_(float x) { return 1.0f / (1.0f + expf(-x)); }

// ---------------- CSR build ----------------
// hist of dst (cols) + role histogram (ballot-aggregated), one pass.
__global__ __launch_bounds__(256) void hist_kernel(const int* __restrict__ ei, const int* __restrict__ role,
                                                   int* __restrict__ cnt, int* __restrict__ rolecnt,
                                                   int E, int N)
{
  int i = blockIdx.x * 256 + threadIdx.x;
  int lane = threadIdx.x & 63;
  int r = (i < N) ? role[i] : -1;
  #pragma unroll
  for (int rr = 0; rr < 3; ++rr) {
    unsigned long long mask = __ballot(r == rr);
    if (lane == 0 && mask) atomicAdd(&rolecnt[rr], __popcll(mask));
  }
  if (i < E + N) {
    int c = (i < E) ? ei[E + i] : (i - E);
    atomicAdd(&cnt[c], 1);
  }
}

// hierarchical scan: scan1 per-block inclusive + block sums
__global__ __launch_bounds__(1024) void scan1_kernel(const int* __restrict__ cnt, int* __restrict__ off,
                                                     int* __restrict__ bsum, int n)
{
  __shared__ int wsum[16];
  int t = threadIdx.x, lane = t & 63, w = t >> 6;
  int idx = blockIdx.x * 1024 + t;
  int v = (idx < n) ? cnt[idx] : 0;
  int s = v;
  #pragma unroll
  for (int d = 1; d < 64; d <<= 1) { int u = __shfl_up(s, d); if (lane >= d) s += u; }
  if (lane == 63) wsum[w] = s;
  __syncthreads();
  if (w == 0 && lane < 16) {
    int ws = wsum[lane];
    #pragma unroll
    for (int d = 1; d < 16; d <<= 1) { int u = __shfl_up(ws, d); if (lane >= d) ws += u; }
    wsum[lane] = ws;
  }
  __syncthreads();
  int inc = ((w > 0) ? wsum[w - 1] : 0) + s;
  if (idx < n) off[idx + 1] = inc;
  if (t == 1023) bsum[blockIdx.x] = inc;
}

// scan2: exclusive-scan block sums (single wave, chunked) + role offsets (256-aligned regions)
__global__ void scan2_kernel(int* __restrict__ bsum, int nb, const int* __restrict__ rolecnt,
                             int* __restrict__ rolefill, int* __restrict__ roleinfo)
{
  int lane = threadIdx.x;
  int carry = 0;
  for (int base = 0; base < nb; base += 64) {
    int v = (base + lane < nb) ? bsum[base + lane] : 0;
    int s = v;
    #pragma unroll
    for (int d = 1; d < 64; d <<= 1) { int u = __shfl_up(s, d); if (lane >= d) s += u; }
    if (base + lane < nb) bsum[base + lane] = carry + s - v;
    carry += __shfl(s, 63);
  }
  if (lane == 0) {
    int c0 = rolecnt[0], c1 = rolecnt[1], c2 = rolecnt[2];
    int s1 = (c0 + 255) & ~255;
    int s2 = s1 + ((c1 + 255) & ~255);
    int mp = s2 + ((c2 + 255) & ~255);
    rolefill[0] = 0; rolefill[1] = s1; rolefill[2] = s2;
    roleinfo[0] = s1; roleinfo[1] = s2;
    roleinfo[2] = c0;      roleinfo[3] = s1 - c0;
    roleinfo[4] = s1 + c1; roleinfo[5] = s2 - s1 - c1;
    roleinfo[6] = s2 + c2; roleinfo[7] = mp - s2 - c2;
  }
}

// scan3: add block offsets, materialize fill = off
__global__ __launch_bounds__(1024) void scan3_kernel(int* __restrict__ off, int* __restrict__ fill,
                                                     const int* __restrict__ bsum, int n)
{
  int idx = blockIdx.x * 1024 + threadIdx.x;
  if (idx == 0) { off[0] = 0; fill[0] = 0; }
  if (idx < n) {
    int v = off[idx + 1] + bsum[blockIdx.x];
    off[idx + 1] = v;
    if (idx + 1 < n) fill[idx + 1] = v;
  }
}

// ssrc stores spos[src]  (role(src) = compares vs s1/s2)
__global__ __launch_bounds__(256) void scatter_kernel(const int* __restrict__ ei, const int* __restrict__ spos,
                                                      int* __restrict__ fill, int* __restrict__ ssrc, int E, int N)
{
  int i = blockIdx.x * 256 + threadIdx.x;
  if (i < E + N) {
    int c, r;
    if (i < E) { c = ei[E + i]; r = ei[i]; } else { c = i - E; r = i - E; }
    int pz = atomicAdd(&fill[c], 1);
    ssrc[pz] = spos[r];
  }
}

__global__ __launch_bounds__(256) void permscatter_kernel(const int* __restrict__ role, int* __restrict__ rolefill,
                                                          int* __restrict__ spos, int N)
{
  int i = blockIdx.x * 256 + threadIdx.x;
  int lane = threadIdx.x & 63;
  int r = (i < N) ? role[i] : -1;
  #pragma unroll
  for (int rr = 0; rr < 3; ++rr) {
    unsigned long long mask = __ballot(r == rr);
    if (!mask) continue;
    int base = 0;
    if (lane == 0) base = atomicAdd(&rolefill[rr], __popcll(mask));
    base = __shfl(base, 0);
    if (r == rr) {
      int rank = (int)__popcll(mask & ((1ull << lane) - 1ull));
      spos[i] = base + rank;
    }
  }
}

// zero pad rows of Ax, Ah (gaps up to 255 rows). 2 arrays x 3 gaps x 256 rows x 64 chunks.
__global__ __launch_bounds__(256) void zeropad_kernel(const int* __restrict__ roleinfo,
                                                      bf16* __restrict__ Ax, bf16* __restrict__ Ah)
{
  int id = blockIdx.x * 256 + threadIdx.x;   // 98304
  int a = id / 49152, rem = id % 49152;
  int gp = rem / 16384, r2 = rem % 16384;
  int rr = r2 >> 6, c = r2 & 63;
  int gs = roleinfo[2 + gp * 2], gl = roleinfo[3 + gp * 2];
  if (rr < gl) {
    int row = gs + rr;
    size_t unit = (size_t)(row >> 4) * 1024 + c * 16 + (row & 15);
    bf16x8 z = {};
    ((bf16x8*)(a == 0 ? Ax : Ah))[unit] = z;
  }
}

// ---------------- prep ----------------
// xq8: role-sorted [t][256] fp8 (x cols 0-127, h cols 128-255); self bf16 frags into Ax/Ah.
__global__ __launch_bounds__(256) void prep_xh_kernel(const float* __restrict__ x, const float* __restrict__ h,
                                                      const int* __restrict__ spos, u8* __restrict__ xq8,
                                                      bf16* __restrict__ Ax, bf16* __restrict__ Ah, int N)
{
  int g = blockIdx.x * 256 + threadIdx.x;
  if (g >= N * 32) return;
  int n = g >> 5, j = g & 31;
  int t = spos[n];
  const float* src = (j < 16) ? (x + (size_t)n * 128 + (j << 3))
                              : (h + (size_t)n * 128 + ((j - 16) << 3));
  float4 v0 = ((const float4*)src)[0];
  float4 v1 = ((const float4*)src)[1];
  int lo = __builtin_amdgcn_cvt_pk_fp8_f32(v0.x, v0.y, 0, false);
  lo = __builtin_amdgcn_cvt_pk_fp8_f32(v0.z, v0.w, lo, true);
  int hi = __builtin_amdgcn_cvt_pk_fp8_f32(v1.x, v1.y, 0, false);
  hi = __builtin_amdgcn_cvt_pk_fp8_f32(v1.z, v1.w, hi, true);
  *(int2*)(xq8 + (size_t)t * 256 + j * 8) = make_int2(lo, hi);
  bf16x8 o;
  o[0] = (bf16)v0.x; o[1] = (bf16)v0.y; o[2] = (bf16)v0.z; o[3] = (bf16)v0.w;
  o[4] = (bf16)v1.x; o[5] = (bf16)v1.y; o[6] = (bf16)v1.z; o[7] = (bf16)v1.w;
  size_t unit = (size_t)(t >> 4) * 1024 + (48 + (j & 15)) * 16 + (t & 15);
  ((bf16x8*)(j < 16 ? Ax : Ah))[unit] = o;
}

struct PrepW { const float* W[6]; const float* Wg[6]; const float* bg[6]; };
__global__ __launch_bounds__(256) void prep_wf_kernel(PrepW pw, bf16* __restrict__ Wf)
{
  int idx = blockIdx.x * 256 + threadIdx.x;
  if (idx >= 294912) return;
  int cv = idx / 49152, pos = idx % 49152;
  int ks4q = pos >> 10;
  int col = (pos >> 3) & 127, j = pos & 7;
  int k = (ks4q >> 2) * 32 + (ks4q & 3) * 8 + j;
  int r = k >> 7, kk = k & 127;
  float g = sigmoidf_(pw.Wg[cv][r * 128 + col] + pw.bg[cv][r * 128 + col]);
  Wf[idx] = (bf16)(pw.W[cv][kk * 128 + col] * g);
}

struct PrepP { const float* W[6]; const float* S[6]; };
__global__ __launch_bounds__(128) void prep_pf_kernel(PrepP pp, bf16* __restrict__ Pf)
{
  int b = blockIdx.x;                          // 6*3*128
  int cv = b / 384, rem = b % 384;
  int r = rem >> 7, kp = rem & 127;
  int col = threadIdx.x;
  const float* W = pp.W[cv] + (size_t)kp * 128;
  const float* S = pp.S[cv] + (size_t)r * 16384;
  float sum = 0.f;
  #pragma unroll 4
  for (int j2 = 0; j2 < 128; ++j2) sum += W[j2] * S[j2 * 128 + col];
  size_t o = (size_t)(cv * 3 + r) * 16384 + ((size_t)(kp >> 3) * 128 + col) * 8 + (kp & 7);
  Pf[o] = (bf16)sum;
}

// ---------------- gathers (fp8 source rows, wave per dst node) ----------------
__global__ __launch_bounds__(256) void gather_xh_kernel(
    const u8* __restrict__ xq8, const int* __restrict__ off, const int* __restrict__ ssrc,
    const int* __restrict__ spos, const int* __restrict__ roleinfo,
    bf16* __restrict__ Ax, bf16* __restrict__ Ah, float4* __restrict__ cntf, int N)
{
  __shared__ alignas(16) bf16 lds[4][768];
  int w = threadIdx.x >> 6, lane = threadIdx.x & 63;
  int node = blockIdx.x * 4 + w;
  bool act = node < N;
  int s = 0, e = 0;
  if (act) { s = off[node]; e = off[node + 1]; }
  s = __builtin_amdgcn_readfirstlane(s);
  e = __builtin_amdgcn_readfirstlane(e);
  const int s1 = roleinfo[0], s2 = roleinfo[1];
  const u8* base = xq8 + lane * 4;
  float u0[4] = {0, 0, 0, 0}, u1[4] = {0, 0, 0, 0}, u2[4] = {0, 0, 0, 0};
  int c0 = 0, c1 = 0;

  auto accum = [&](int t, unsigned u) {
    f32x2 f01 = __builtin_amdgcn_cvt_pk_f32_fp8((int)u, false);
    f32x2 f23 = __builtin_amdgcn_cvt_pk_f32_fp8((int)u, true);
    if (t >= s2)      { u2[0] += f01[0]; u2[1] += f01[1]; u2[2] += f23[0]; u2[3] += f23[1]; }
    else if (t >= s1) { u1[0] += f01[0]; u1[1] += f01[1]; u1[2] += f23[0]; u1[3] += f23[1]; c1++; }
    else              { u0[0] += f01[0]; u0[1] += f01[1]; u0[2] += f23[0]; u0[3] += f23[1]; c0++; }
  };

  int i = s;
  for (; i + 8 <= e; i += 8) {
    int t0 = ssrc[i],     t1 = ssrc[i + 1], t2 = ssrc[i + 2], t3 = ssrc[i + 3];
    int t4 = ssrc[i + 4], t5 = ssrc[i + 5], t6 = ssrc[i + 6], t7 = ssrc[i + 7];
    unsigned a0 = *(const unsigned*)(base + (size_t)t0 * 256);
    unsigned a1 = *(const unsigned*)(base + (size_t)t1 * 256);
    unsigned a2 = *(const unsigned*)(base + (size_t)t2 * 256);
    unsigned a3 = *(const unsigned*)(base + (size_t)t3 * 256);
    unsigned a4 = *(const unsigned*)(base + (size_t)t4 * 256);
    unsigned a5 = *(const unsigned*)(base + (size_t)t5 * 256);
    unsigned a6 = *(const unsigned*)(base + (size_t)t6 * 256);
    unsigned a7 = *(const unsigned*)(base + (size_t)t7 * 256);
    accum(t0, a0); accum(t1, a1); accum(t2, a2); accum(t3, a3);
    accum(t4, a4); accum(t5, a5); accum(t6, a6); accum(t7, a7);
  }
  for (; i < e; ++i) {
    int t = ssrc[i];
    accum(t, *(const unsigned*)(base + (size_t)t * 256));
  }

  int deg = e - s;
  float inv = 1.0f / (float)(deg > 0 ? deg : 1);
  int sec = (lane < 32) ? 0 : 384;
  int cid = (lane & 31) * 4;
  #pragma unroll
  for (int k = 0; k < 4; ++k) {
    lds[w][sec + cid + k]       = (bf16)(u0[k] * inv);
    lds[w][sec + 128 + cid + k] = (bf16)(u1[k] * inv);
    lds[w][sec + 256 + cid + k] = (bf16)(u2[k] * inv);
  }
  __syncthreads();
  if (act) {
    int t = spos[node];
    int rb = t >> 4, l16 = t & 15;
    if (lane < 48) {
      size_t unit = (size_t)rb * 1024 + lane * 16 + l16;
      ((bf16x8*)Ax)[unit] = *(const bf16x8*)&lds[w][lane * 8];
      ((bf16x8*)Ah)[unit] = *(const bf16x8*)&lds[w][384 + lane * 8];
    }
    if (lane == 63)
      cntf[t] = make_float4(c0 * inv, c1 * inv, (deg - c0 - c1) * inv, (float)deg);
  }
}

__global__ __launch_bounds__(256) void gather_q_kernel(
    const u8* __restrict__ q8, const int* __restrict__ off, const int* __restrict__ ssrc,
    const int* __restrict__ spos, const int* __restrict__ roleinfo,
    bf16* __restrict__ Aq, int N)
{
  __shared__ alignas(16) bf16 lds[4][384];
  int w = threadIdx.x >> 6, lane = threadIdx.x & 63;
  int node = blockIdx.x * 4 + w;
  bool act = node < N;
  int s = 0, e = 0;
  if (act) { s = off[node]; e = off[node + 1]; }
  s = __builtin_amdgcn_readfirstlane(s);
  e = __builtin_amdgcn_readfirstlane(e);
  const int s1 = roleinfo[0], s2 = roleinfo[1];
  const u8* base = q8 + lane * 2;
  float u0a = 0, u0b = 0, u1a = 0, u1b = 0, u2a = 0, u2b = 0;

  auto accum = [&](int t, unsigned u) {
    f32x2 f = __builtin_amdgcn_cvt_pk_f32_fp8((int)u, false);
    if (t >= s2)      { u2a += f[0]; u2b += f[1]; }
    else if (t >= s1) { u1a += f[0]; u1b += f[1]; }
    else              { u0a += f[0]; u0b += f[1]; }
  };

  int i = s;
  for (; i + 8 <= e; i += 8) {
    int t0 = ssrc[i],     t1 = ssrc[i + 1], t2 = ssrc[i + 2], t3 = ssrc[i + 3];
    int t4 = ssrc[i + 4], t5 = ssrc[i + 5], t6 = ssrc[i + 6], t7 = ssrc[i + 7];
    unsigned a0 = *(const unsigned short*)(base + (size_t)t0 * 128);
    unsigned a1 = *(const unsigned short*)(base + (size_t)t1 * 128);
    unsigned a2 = *(const unsigned short*)(base + (size_t)t2 * 128);
    unsigned a3 = *(const unsigned short*)(base + (size_t)t3 * 128);
    unsigned a4 = *(const unsigned short*)(base + (size_t)t4 * 128);
    unsigned a5 = *(const unsigned short*)(base + (size_t)t5 * 128);
    unsigned a6 = *(const unsigned short*)(base + (size_t)t6 * 128);
    unsigned a7 = *(const unsigned short*)(base + (size_t)t7 * 128);
    accum(t0, a0); accum(t1, a1); accum(t2, a2); accum(t3, a3);
    accum(t4, a4); accum(t5, a5); accum(t6, a6); accum(t7, a7);
  }
  for (; i < e; ++i) {
    int t = ssrc[i];
    accum(t, *(const unsigned short*)(base + (size_t)t * 128));
  }

  float inv = 1.0f / (float)(e - s > 0 ? e - s : 1);
  int c2 = lane * 2;
  lds[w][c2]       = (bf16)(u0a * inv); lds[w][c2 + 1]       = (bf16)(u0b * inv);
  lds[w][128 + c2] = (bf16)(u1a * inv); lds[w][128 + c2 + 1] = (bf16)(u1b * inv);
  lds[w][256 + c2] = (bf16)(u2a * inv); lds[w][256 + c2 + 1] = (bf16)(u2b * inv);
  __syncthreads();
  if (act && lane < 48) {
    int t = spos[node];
    size_t unit = (size_t)(t >> 4) * 1024 + lane * 16 + (t & 15);
    ((bf16x8*)Aq)[unit] = *(const bf16x8*)&lds[w][lane * 8];
  }
}

// ---------------- streaming MFMA GEMM (no LDS/barriers; 4 row-blocks per wave) ----------------
struct GArgs {
  const bf16* Ap[5];
  const bf16* wf[5];
  const bf16* pf[5];
  bf16* out[5];
  const float* bias[5];
};

__global__ __launch_bounds__(256) void gemm_kernel(GArgs ga, const float4* __restrict__ cntf,
                                                   const int* __restrict__ roleinfo)
{
  const int cv = blockIdx.y;
  const bf16* __restrict__ Ap = ga.Ap[cv];
  const bf16* __restrict__ wf = ga.wf[cv];
  const bf16* __restrict__ pf = ga.pf[cv];
  bf16* __restrict__ out = ga.out[cv];
  const float* __restrict__ bias = ga.bias[cv];

  const int w = threadIdx.x >> 6, lane = threadIdx.x & 63;
  const int q = lane >> 4, l = lane & 15;
  const int rb0 = blockIdx.x * 16 + w * 4;
  const int row0 = blockIdx.x * 256;
  const int s1 = roleinfo[0], s2 = roleinfo[1];
  const int role = (row0 >= s2) ? 2 : (row0 >= s1) ? 1 : 0;
  const int laneoff = q * 128 + l;

  f32x4 acc[4][8];
  #pragma unroll
  for (int j = 0; j < 4; ++j)
    #pragma unroll
    for (int ct = 0; ct < 8; ++ct)
      #pragma unroll
      for (int k = 0; k < 4; ++k) acc[j][ct][k] = 0.f;

  const bf16x8* A0 = (const bf16x8*)Ap + (size_t)rb0 * 1024 + lane;
  const bf16x8* WF = (const bf16x8*)wf + laneoff;
  const bf16x8* PF = (const bf16x8*)pf + role * 2048 + laneoff;

  #pragma unroll 2
  for (int ks = 0; ks < 16; ++ks) {
    const bf16x8* bp = (ks < 12) ? (WF + ks * 512) : (PF + (ks - 12) * 512);
    bf16x8 a0 = A0[ks * 64];
    bf16x8 a1 = A0[1024 + ks * 64];
    bf16x8 a2 = A0[2048 + ks * 64];
    bf16x8 a3 = A0[3072 + ks * 64];
    #pragma unroll
    for (int ct = 0; ct < 8; ++ct) {
      bf16x8 b = bp[ct * 16];
      acc[0][ct] = __builtin_amdgcn_mfma_f32_16x16x32_bf16(a0, b, acc[0][ct], 0, 0, 0);
      acc[1][ct] = __builtin_amdgcn_mfma_f32_16x16x32_bf16(a1, b, acc[1][ct], 0, 0, 0);
      acc[2][ct] = __builtin_amdgcn_mfma_f32_16x16x32_bf16(a2, b, acc[2][ct], 0, 0, 0);
      acc[3][ct] = __builtin_amdgcn_mfma_f32_16x16x32_bf16(a3, b, acc[3][ct], 0, 0, 0);
    }
  }

  const bool hb = (bias != nullptr);
  #pragma unroll
  for (int j = 0; j < 4; ++j) {
    int rb = rb0 + j;
    float4 cfs[4];
    if (hb) {
      #pragma unroll
      for (int reg = 0; reg < 4; ++reg) cfs[reg] = cntf[rb * 16 + q * 4 + reg];
    }
    #pragma unroll
    for (int ct = 0; ct < 8; ++ct) {
      int col = ct * 16 + l;
      float b0 = 0, b1 = 0, b2 = 0;
      if (hb) { b0 = bias[col]; b1 = bias[128 + col]; b2 = bias[256 + col]; }
      #pragma unroll
      for (int reg = 0; reg < 4; ++reg) {
        int t = rb * 16 + q * 4 + reg;
        float v = acc[j][ct][reg];
        if (hb) v += cfs[reg].x * b0 + cfs[reg].y * b1 + cfs[reg].z * b2;
        out[(size_t)t * 128 + col] = (bf16)fmaxf(v, 0.f);
      }
    }
  }
}

// ---------------- combines ----------------
__global__ __launch_bounds__(256) void combine1_kernel(
    const bf16* __restrict__ o0, const bf16* __restrict__ o1,
    const bf16* __restrict__ o2, const bf16* __restrict__ o3,
    const float* __restrict__ h, const int* __restrict__ spos,
    float* __restrict__ zbuf, u8* __restrict__ q8, bf16* __restrict__ Aq, int N)
{
  int g = blockIdx.x * 256 + threadIdx.x;
  if (g >= N * 16) return;
  int n = g >> 4, o = g & 15;
  int t = spos[n];
  size_t tb = (size_t)t * 16 + o;
  bf16x8 a0 = ((const bf16x8*)o0)[tb];
  bf16x8 a1 = ((const bf16x8*)o1)[tb];
  bf16x8 a2 = ((const bf16x8*)o2)[tb];
  bf16x8 a3 = ((const bf16x8*)o3)[tb];
  size_t nb = (size_t)n * 16 + o;
  float4 h0 = ((const float4*)h)[nb * 2];
  float4 h1 = ((const float4*)h)[nb * 2 + 1];
  float hv[8] = {h0.x, h0.y, h0.z, h0.w, h1.x, h1.y, h1.z, h1.w};
  float zv[8], qv[8];
  bf16x8 qb;
  #pragma unroll
  for (int j = 0; j < 8; ++j) {
    zv[j] = sigmoidf_((float)a0[j] + (float)a1[j]);
    qv[j] = sigmoidf_((float)a2[j] + (float)a3[j]) * hv[j];
    qb[j] = (bf16)qv[j];
  }
  ((float4*)zbuf)[nb * 2]     = make_float4(zv[0], zv[1], zv[2], zv[3]);
  ((float4*)zbuf)[nb * 2 + 1] = make_float4(zv[4], zv[5], zv[6], zv[7]);
  int lo = __builtin_amdgcn_cvt_pk_fp8_f32(qv[0], qv[1], 0, false);
  lo = __builtin_amdgcn_cvt_pk_fp8_f32(qv[2], qv[3], lo, true);
  int hi = __builtin_amdgcn_cvt_pk_fp8_f32(qv[4], qv[5], 0, false);
  hi = __builtin_amdgcn_cvt_pk_fp8_f32(qv[6], qv[7], hi, true);
  *(int2*)(q8 + (size_t)t * 128 + o * 8) = make_int2(lo, hi);
  size_t unit = (size_t)(t >> 4) * 1024 + (48 + o) * 16 + (t & 15);
  ((bf16x8*)Aq)[unit] = qb;
}

__global__ __launch_bounds__(256) void combine2_kernel(
    const float* __restrict__ zbuf, const bf16* __restrict__ o4, const bf16* __restrict__ o5,
    const float* __restrict__ h, const int* __restrict__ spos, float* __restrict__ out, int N)
{
  int g = blockIdx.x * 256 + threadIdx.x;
  if (g >= N * 16) return;
  int n = g >> 4, o = g & 15;
  int t = spos[n];
  size_t tb = (size_t)t * 16 + o;
  bf16x8 a = ((const bf16x8*)o4)[tb];
  bf16x8 b = ((const bf16x8*)o5)[tb];
  size_t nb = (size_t)n * 16 + o;
  float4 z0 = ((const float4*)zbuf)[nb * 2];
  float4 z1 = ((const float4*)zbuf)[nb * 2 + 1];
  float4 h0 = ((const float4*)h)[nb * 2];
  float4 h1 = ((const float4*)h)[nb * 2 + 1];
  float zv[8] = {z0.x, z0.y, z0.z, z0.w, z1.x, z1.y, z1.z, z1.w};
  float hv[8] = {h0.x, h0.y, h0.z, h0.w, h1.x, h1.y, h1.z, h1.w};
  float ov[8];
  #pragma unroll
  for (int j = 0; j < 8; ++j)
    ov[j] = zv[j] * hv[j] + (1.f - zv[j]) * tanhf((float)a[j] + (float)b[j]);
  ((float4*)out)[nb * 2]     = make_float4(ov[0], ov[1], ov[2], ov[3]);
  ((float4*)out)[nb * 2 + 1] = make_float4(ov[4], ov[5], ov[6], ov[7]);
}

// ---------------- host ----------------
extern "C" void kernel_launch(void* const* d_in, const int* in_sizes, int n_in,
                              void* d_out, int out_size, void* d_ws, size_t ws_size,
                              hipStream_t stream)
{
  (void)n_in; (void)out_size; (void)ws_size;
  const float* x    = (const float*)d_in[0];
  const float* h    = (const float*)d_in[1];
  const int*   ei   = (const int*)d_in[2];
  const int*   role = (const int*)d_in[3];
  const int N = in_sizes[0] / DH;
  const int E = in_sizes[2] / 2;
  const int Etot = E + N;
  const int rows_pad = ((N + 765) + 255) & ~255;
  const int gx = rows_pad / 256;
  const int nb = (N + 1023) / 1024;

  // conv order: 0 xz, 1 hz, 2 xr, 3 hr, 4 xh, 5 hh
  static const int Wi[6]  = {4, 9, 13, 18, 22, 27};
  static const int Wgi[6] = {5, 10, 14, 19, 23, 28};
  static const int bgi[6] = {6, 11, 15, 20, 24, 29};
  static const int Si[6]  = {7, 12, 16, 21, 25, 30};

  char* p = (char*)d_ws;
  auto alloc = [&](size_t bytes) -> char* {
    char* r = p;
    p += (bytes + 255) & ~(size_t)255;
    return r;
  };

  bf16* Ax = (bf16*)alloc((size_t)rows_pad * 512 * 2);   // Aq aliases Ax
  bf16* Ah = (bf16*)alloc((size_t)rows_pad * 512 * 2);
  bf16* Aq = Ax;
  u8* xq8  = (u8*)alloc((size_t)rows_pad * 256);
  u8* q8   = (u8*)alloc((size_t)rows_pad * 128);
  bf16* outs[6];
  for (int c = 0; c < 5; ++c) outs[c] = (bf16*)alloc((size_t)rows_pad * 128 * 2);
  outs[5] = outs[0];
  float* zbuf = (float*)alloc((size_t)N * 128 * 4);
  float4* cntf = (float4*)alloc((size_t)rows_pad * 16);
  bf16* Wf = (bf16*)alloc((size_t)6 * 49152 * 2);
  bf16* Pf = (bf16*)alloc((size_t)18 * 16384 * 2);
  int* cnt   = (int*)alloc((size_t)N * 4);
  int* off   = (int*)alloc((size_t)(N + 1) * 4);
  int* fill  = (int*)alloc((size_t)N * 4);
  int* bsum  = (int*)alloc((size_t)(nb + 1) * 4);
  int* ssrc  = (int*)alloc((size_t)Etot * 4);
  int* spos  = (int*)alloc((size_t)N * 4);
  int* rolecnt  = (int*)alloc(64);
  int* rolefill = (int*)alloc(64);
  int* roleinfo = (int*)alloc(64);

  hipMemsetAsync(cnt, 0, (size_t)N * 4, stream);
  hipMemsetAsync(rolecnt, 0, 16, stream);

  int egrid = (Etot + 255) / 256;
  int ngrid = (N + 255) / 256;
  hist_kernel<<<egrid, 256, 0, stream>>>(ei, role, cnt, rolecnt, E, N);
  scan1_kernel<<<nb, 1024, 0, stream>>>(cnt, off, bsum, N);
  scan2_kernel<<<1, 64, 0, stream>>>(bsum, nb, rolecnt, rolefill, roleinfo);
  scan3_kernel<<<nb, 1024, 0, stream>>>(off, fill, bsum, N);
  permscatter_kernel<<<ngrid, 256, 0, stream>>>(role, rolefill, spos, N);
  scatter_kernel<<<egrid, 256, 0, stream>>>(ei, spos, fill, ssrc, E, N);
  zeropad_kernel<<<384, 256, 0, stream>>>(roleinfo, Ax, Ah);

  prep_xh_kernel<<<(N * 32 + 255) / 256, 256, 0, stream>>>(x, h, spos, xq8, Ax, Ah, N);

  PrepW pw;
  for (int c = 0; c < 6; ++c) {
    pw.W[c] = (const float*)d_in[Wi[c]];
    pw.Wg[c] = (const float*)d_in[Wgi[c]];
    pw.bg[c] = (const float*)d_in[bgi[c]];
  }
  prep_wf_kernel<<<1152, 256, 0, stream>>>(pw, Wf);
  PrepP pp;
  for (int c = 0; c < 6; ++c) { pp.W[c] = (const float*)d_in[Wi[c]]; pp.S[c] = (const float*)d_in[Si[c]]; }
  prep_pf_kernel<<<2304, 128, 0, stream>>>(pp, Pf);

  gather_xh_kernel<<<(N + 3) / 4, 256, 0, stream>>>(xq8, off, ssrc, spos, roleinfo, Ax, Ah, cntf, N);

  // pass 1: one dispatch, cv 0..4 = {xz,xr,xh on Ax (bias)} + {hz,hr on Ah}
  GArgs g0;
  { int cvs[5] = {0, 2, 4, 1, 3};
    static const int bi2[5] = {8, 17, 26, -1, -1};
    const bf16* Apts[5] = {Ax, Ax, Ax, Ah, Ah};
    for (int k = 0; k < 5; ++k) {
      int c = cvs[k];
      g0.Ap[k] = Apts[k];
      g0.wf[k] = Wf + (size_t)c * 49152;
      g0.pf[k] = Pf + (size_t)c * 3 * 16384;
      g0.out[k] = outs[c];
      g0.bias[k] = (bi2[k] >= 0) ? (const float*)d_in[bi2[k]] : nullptr;
    } }
  gemm_kernel<<<dim3(gx, 5), 256, 0, stream>>>(g0, cntf, roleinfo);

  combine1_kernel<<<(N * 16 + 255) / 256, 256, 0, stream>>>(outs[0], outs[1], outs[2], outs[3],
                                                            h, spos, zbuf, q8, Aq, N);

  gather_q_kernel<<<(N + 3) / 4, 256, 0, stream>>>(q8, off, ssrc, spos, roleinfo, Aq, N);

  // pass 2: conv hh(5) on Aq
  GArgs g2 = {};
  g2.Ap[0] = Aq;
  g2.wf[0] = Wf + (size_t)5 * 49152;
  g2.pf[0] = Pf + (size_t)5 * 3 * 16384;
  g2.out[0] = outs[5];
  g2.bias[0] = nullptr;
  gemm_kernel<<<dim3(gx, 1), 256, 0, stream>>>(g2, cntf, roleinfo);

  combine2_kernel<<<(N * 16 + 255) / 256, 256, 0, stream>>>(zbuf, outs[4], outs[5], h, spos,
                                                            (float*)d_out, N);
}

// Round 6
// 773.504 us; speedup vs baseline: 1.5293x; 1.0117x over previous
//
#include <hip/hip_runtime.h>

// GraphGRU on MI355X — round 6.
//   Quarter-wave gathers: 4 edges per VMEM instr (16 lanes/row; dwordx4 for 256B x|h row,
//   dwordx2 for 128B q row), shfl_xor merge. CSR binned by (dst, role(src)) -> 3 role-uniform
//   segments per node, no per-edge role logic; cnt_r from offsets.
//   GEMM unchanged (streaming barrier-free MFMA, 4 row-blocks/wave, role-uniform 256-blocks).

typedef __bf16 bf16;
typedef __bf16 bf16x8 __attribute__((ext_vector_type(8)));
typedef float  f32x4  __attribute__((ext_vector_type(4)));
typedef float  f32x2  __attribute__((ext_vector_type(2)));
typedef unsigned char u8;

#define DH 128

__device__ __forceinline__ float sigmoidf_(float x) { return 1.0f / (1.0f + expf(-x)); }

// ---------------- CSR build ----------------
// cnt3 bins: dst*3 + role(src). Also role histogram of nodes (ballot-aggregated).
__global__ __launch_bounds__(256) void hist_kernel(const int* __restrict__ ei, const int* __restrict__ role,
                                                   int* __restrict__ cnt3, int* __restrict__ rolecnt,
                                                   int E, int N)
{
  int i = blockIdx.x * 256 + threadIdx.x;
  int lane = threadIdx.x & 63;
  int r = (i < N) ? role[i] : -1;
  #pragma unroll
  for (int rr = 0; rr < 3; ++rr) {
    unsigned long long mask = __ballot(r == rr);
    if (lane == 0 && mask) atomicAdd(&rolecnt[rr], __popcll(mask));
  }
  if (i < E + N) {
    int src, dst;
    if (i < E) { src = ei[i]; dst = ei[E + i]; } else { src = i - E; dst = i - E; }
    int rs = (i < E) ? role[src] : r;     // self part: role[i-E] == r when i-E == i (i>=E path recompute)
    if (i >= E) rs = role[i - E];
    atomicAdd(&cnt3[dst * 3 + rs], 1);
  }
}

// hierarchical scan over n bins
__global__ __launch_bounds__(1024) void scan1_kernel(const int* __restrict__ cnt, int* __restrict__ off,
                                                     int* __restrict__ bsum, int n)
{
  __shared__ int wsum[16];
  int t = threadIdx.x, lane = t & 63, w = t >> 6;
  int idx = blockIdx.x * 1024 + t;
  int v = (idx < n) ? cnt[idx] : 0;
  int s = v;
  #pragma unroll
  for (int d = 1; d < 64; d <<= 1) { int u = __shfl_up(s, d); if (lane >= d) s += u; }
  if (lane == 63) wsum[w] = s;
  __syncthreads();
  if (w == 0 && lane < 16) {
    int ws = wsum[lane];
    #pragma unroll
    for (int d = 1; d < 16; d <<= 1) { int u = __shfl_up(ws, d); if (lane >= d) ws += u; }
    wsum[lane] = ws;
  }
  __syncthreads();
  int inc = ((w > 0) ? wsum[w - 1] : 0) + s;
  if (idx < n) off[idx + 1] = inc;
  if (t == 1023) bsum[blockIdx.x] = inc;
}

__global__ void scan2_kernel(int* __restrict__ bsum, int nb, const int* __restrict__ rolecnt,
                             int* __restrict__ rolefill, int* __restrict__ roleinfo)
{
  int lane = threadIdx.x;
  int carry = 0;
  for (int base = 0; base < nb; base += 64) {
    int v = (base + lane < nb) ? bsum[base + lane] : 0;
    int s = v;
    #pragma unroll
    for (int d = 1; d < 64; d <<= 1) { int u = __shfl_up(s, d); if (lane >= d) s += u; }
    if (base + lane < nb) bsum[base + lane] = carry + s - v;
    carry += __shfl(s, 63);
  }
  if (lane == 0) {
    int c0 = rolecnt[0], c1 = rolecnt[1], c2 = rolecnt[2];
    int s1 = (c0 + 255) & ~255;
    int s2 = s1 + ((c1 + 255) & ~255);
    int mp = s2 + ((c2 + 255) & ~255);
    rolefill[0] = 0; rolefill[1] = s1; rolefill[2] = s2;
    roleinfo[0] = s1; roleinfo[1] = s2;
    roleinfo[2] = c0;      roleinfo[3] = s1 - c0;
    roleinfo[4] = s1 + c1; roleinfo[5] = s2 - s1 - c1;
    roleinfo[6] = s2 + c2; roleinfo[7] = mp - s2 - c2;
  }
}

__global__ __launch_bounds__(1024) void scan3_kernel(int* __restrict__ off, int* __restrict__ fill,
                                                     const int* __restrict__ bsum, int n)
{
  int idx = blockIdx.x * 1024 + threadIdx.x;
  if (idx == 0) { off[0] = 0; fill[0] = 0; }
  if (idx < n) {
    int v = off[idx + 1] + bsum[blockIdx.x];
    off[idx + 1] = v;
    if (idx + 1 < n) fill[idx + 1] = v;
  }
}

// ssrc stores spos[src]; bin role derived from spos vs s1/s2
__global__ __launch_bounds__(256) void scatter_kernel(const int* __restrict__ ei, const int* __restrict__ spos,
                                                      const int* __restrict__ roleinfo,
                                                      int* __restrict__ fill3, int* __restrict__ ssrc, int E, int N)
{
  int i = blockIdx.x * 256 + threadIdx.x;
  if (i >= E + N) return;
  int s1 = roleinfo[0], s2 = roleinfo[1];
  int src, dst;
  if (i < E) { src = ei[i]; dst = ei[E + i]; } else { src = i - E; dst = i - E; }
  int t = spos[src];
  int r = (t >= s2) ? 2 : (t >= s1) ? 1 : 0;
  int pz = atomicAdd(&fill3[dst * 3 + r], 1);
  ssrc[pz] = t;
}

__global__ __launch_bounds__(256) void permscatter_kernel(const int* __restrict__ role, int* __restrict__ rolefill,
                                                          int* __restrict__ spos, int N)
{
  int i = blockIdx.x * 256 + threadIdx.x;
  int lane = threadIdx.x & 63;
  int r = (i < N) ? role[i] : -1;
  #pragma unroll
  for (int rr = 0; rr < 3; ++rr) {
    unsigned long long mask = __ballot(r == rr);
    if (!mask) continue;
    int base = 0;
    if (lane == 0) base = atomicAdd(&rolefill[rr], __popcll(mask));
    base = __shfl(base, 0);
    if (r == rr) {
      int rank = (int)__popcll(mask & ((1ull << lane) - 1ull));
      spos[i] = base + rank;
    }
  }
}

__global__ __launch_bounds__(256) void zeropad_kernel(const int* __restrict__ roleinfo,
                                                      bf16* __restrict__ Ax, bf16* __restrict__ Ah)
{
  int id = blockIdx.x * 256 + threadIdx.x;   // 98304
  int a = id / 49152, rem = id % 49152;
  int gp = rem / 16384, r2 = rem % 16384;
  int rr = r2 >> 6, c = r2 & 63;
  int gs = roleinfo[2 + gp * 2], gl = roleinfo[3 + gp * 2];
  if (rr < gl) {
    int row = gs + rr;
    size_t unit = (size_t)(row >> 4) * 1024 + c * 16 + (row & 15);
    bf16x8 z = {};
    ((bf16x8*)(a == 0 ? Ax : Ah))[unit] = z;
  }
}

// ---------------- prep ----------------
__global__ __launch_bounds__(256) void prep_xh_kernel(const float* __restrict__ x, const float* __restrict__ h,
                                                      const int* __restrict__ spos, u8* __restrict__ xq8,
                                                      bf16* __restrict__ Ax, bf16* __restrict__ Ah, int N)
{
  int g = blockIdx.x * 256 + threadIdx.x;
  if (g >= N * 32) return;
  int n = g >> 5, j = g & 31;
  int t = spos[n];
  const float* src = (j < 16) ? (x + (size_t)n * 128 + (j << 3))
                              : (h + (size_t)n * 128 + ((j - 16) << 3));
  float4 v0 = ((const float4*)src)[0];
  float4 v1 = ((const float4*)src)[1];
  int lo = __builtin_amdgcn_cvt_pk_fp8_f32(v0.x, v0.y, 0, false);
  lo = __builtin_amdgcn_cvt_pk_fp8_f32(v0.z, v0.w, lo, true);
  int hi = __builtin_amdgcn_cvt_pk_fp8_f32(v1.x, v1.y, 0, false);
  hi = __builtin_amdgcn_cvt_pk_fp8_f32(v1.z, v1.w, hi, true);
  *(int2*)(xq8 + (size_t)t * 256 + j * 8) = make_int2(lo, hi);
  bf16x8 o;
  o[0] = (bf16)v0.x; o[1] = (bf16)v0.y; o[2] = (bf16)v0.z; o[3] = (bf16)v0.w;
  o[4] = (bf16)v1.x; o[5] = (bf16)v1.y; o[6] = (bf16)v1.z; o[7] = (bf16)v1.w;
  size_t unit = (size_t)(t >> 4) * 1024 + (48 + (j & 15)) * 16 + (t & 15);
  ((bf16x8*)(j < 16 ? Ax : Ah))[unit] = o;
}

struct PrepW { const float* W[6]; const float* Wg[6]; const float* bg[6]; };
__global__ __launch_bounds__(256) void prep_wf_kernel(PrepW pw, bf16* __restrict__ Wf)
{
  int idx = blockIdx.x * 256 + threadIdx.x;
  if (idx >= 294912) return;
  int cv = idx / 49152, pos = idx % 49152;
  int ks4q = pos >> 10;
  int col = (pos >> 3) & 127, j = pos & 7;
  int k = (ks4q >> 2) * 32 + (ks4q & 3) * 8 + j;
  int r = k >> 7, kk = k & 127;
  float g = sigmoidf_(pw.Wg[cv][r * 128 + col] + pw.bg[cv][r * 128 + col]);
  Wf[idx] = (bf16)(pw.W[cv][kk * 128 + col] * g);
}

struct PrepP { const float* W[6]; const float* S[6]; };
__global__ __launch_bounds__(128) void prep_pf_kernel(PrepP pp, bf16* __restrict__ Pf)
{
  int b = blockIdx.x;                          // 6*3*128
  int cv = b / 384, rem = b % 384;
  int r = rem >> 7, kp = rem & 127;
  int col = threadIdx.x;
  const float* W = pp.W[cv] + (size_t)kp * 128;
  const float* S = pp.S[cv] + (size_t)r * 16384;
  float sum = 0.f;
  #pragma unroll 4
  for (int j2 = 0; j2 < 128; ++j2) sum += W[j2] * S[j2 * 128 + col];
  size_t o = (size_t)(cv * 3 + r) * 16384 + ((size_t)(kp >> 3) * 128 + col) * 8 + (kp & 7);
  Pf[o] = (bf16)sum;
}

// ---------------- gathers (quarter-wave: 4 edges per VMEM instr) ----------------
__global__ __launch_bounds__(256) void gather_xh_kernel(
    const u8* __restrict__ xq8, const int* __restrict__ off3, const int* __restrict__ ssrc,
    const int* __restrict__ spos, bf16* __restrict__ Ax, bf16* __restrict__ Ah,
    float4* __restrict__ cntf, int N)
{
  __shared__ alignas(16) bf16 lds[4][768];
  int w = threadIdx.x >> 6, lane = threadIdx.x & 63;
  int node = blockIdx.x * 4 + w;
  if (node >= N) return;
  int qt = lane >> 4, ql = lane & 15;
  int o0 = __builtin_amdgcn_readfirstlane(off3[node * 3]);
  int o1 = __builtin_amdgcn_readfirstlane(off3[node * 3 + 1]);
  int o2 = __builtin_amdgcn_readfirstlane(off3[node * 3 + 2]);
  int o3 = __builtin_amdgcn_readfirstlane(off3[node * 3 + 3]);
  float inv = 1.0f / (float)(o3 - o0);
  const u8* base = xq8 + ql * 16;
  int segs[4] = {o0, o1, o2, o3};

  #pragma unroll
  for (int rr = 0; rr < 3; ++rr) {
    int s = segs[rr], e = segs[rr + 1];
    float u[16];
    #pragma unroll
    for (int k = 0; k < 16; ++k) u[k] = 0.f;

    auto accum = [&](int4 d) {
      f32x2 f;
      f = __builtin_amdgcn_cvt_pk_f32_fp8(d.x, false); u[0] += f[0];  u[1] += f[1];
      f = __builtin_amdgcn_cvt_pk_f32_fp8(d.x, true);  u[2] += f[0];  u[3] += f[1];
      f = __builtin_amdgcn_cvt_pk_f32_fp8(d.y, false); u[4] += f[0];  u[5] += f[1];
      f = __builtin_amdgcn_cvt_pk_f32_fp8(d.y, true);  u[6] += f[0];  u[7] += f[1];
      f = __builtin_amdgcn_cvt_pk_f32_fp8(d.z, false); u[8] += f[0];  u[9] += f[1];
      f = __builtin_amdgcn_cvt_pk_f32_fp8(d.z, true);  u[10] += f[0]; u[11] += f[1];
      f = __builtin_amdgcn_cvt_pk_f32_fp8(d.w, false); u[12] += f[0]; u[13] += f[1];
      f = __builtin_amdgcn_cvt_pk_f32_fp8(d.w, true);  u[14] += f[0]; u[15] += f[1];
    };

    int i = s;
    for (; i + 16 <= e; i += 16) {
      int t0 = ssrc[i + qt];
      int t1 = ssrc[i + 4 + qt];
      int t2 = ssrc[i + 8 + qt];
      int t3 = ssrc[i + 12 + qt];
      int4 d0 = *(const int4*)(base + (size_t)t0 * 256);
      int4 d1 = *(const int4*)(base + (size_t)t1 * 256);
      int4 d2 = *(const int4*)(base + (size_t)t2 * 256);
      int4 d3 = *(const int4*)(base + (size_t)t3 * 256);
      accum(d0); accum(d1); accum(d2); accum(d3);
    }
    for (; i + 4 <= e; i += 4) {
      int t = ssrc[i + qt];
      int4 d = *(const int4*)(base + (size_t)t * 256);
      accum(d);
    }
    if (qt < e - i) {
      int t = ssrc[i + qt];
      int4 d = *(const int4*)(base + (size_t)t * 256);
      accum(d);
    }

    #pragma unroll
    for (int k = 0; k < 16; ++k) {
      u[k] += __shfl_xor(u[k], 16);
      u[k] += __shfl_xor(u[k], 32);
    }
    if (qt == 0) {
      int secbase = (ql < 8) ? (rr * 128 + ql * 16) : (384 + rr * 128 + (ql - 8) * 16);
      bf16x8 p0, p1;
      #pragma unroll
      for (int k = 0; k < 8; ++k) { p0[k] = (bf16)(u[k] * inv); p1[k] = (bf16)(u[8 + k] * inv); }
      *(bf16x8*)&lds[w][secbase] = p0;
      *(bf16x8*)&lds[w][secbase + 8] = p1;
    }
  }

  int t = spos[node];
  if (lane < 48) {
    size_t unit = (size_t)(t >> 4) * 1024 + lane * 16 + (t & 15);
    ((bf16x8*)Ax)[unit] = *(const bf16x8*)&lds[w][lane * 8];
    ((bf16x8*)Ah)[unit] = *(const bf16x8*)&lds[w][384 + lane * 8];
  }
  if (lane == 0)
    cntf[t] = make_float4((o1 - o0) * inv, (o2 - o1) * inv, (o3 - o2) * inv, (float)(o3 - o0));
}

__global__ __launch_bounds__(256) void gather_q_kernel(
    const u8* __restrict__ q8, const int* __restrict__ off3, const int* __restrict__ ssrc,
    const int* __restrict__ spos, bf16* __restrict__ Aq, int N)
{
  __shared__ alignas(16) bf16 lds[4][384];
  int w = threadIdx.x >> 6, lane = threadIdx.x & 63;
  int node = blockIdx.x * 4 + w;
  if (node >= N) return;
  int qt = lane >> 4, ql = lane & 15;
  int o0 = __builtin_amdgcn_readfirstlane(off3[node * 3]);
  int o1 = __builtin_amdgcn_readfirstlane(off3[node * 3 + 1]);
  int o2 = __builtin_amdgcn_readfirstlane(off3[node * 3 + 2]);
  int o3 = __builtin_amdgcn_readfirstlane(off3[node * 3 + 3]);
  float inv = 1.0f / (float)(o3 - o0);
  const u8* base = q8 + ql * 8;
  int segs[4] = {o0, o1, o2, o3};

  #pragma unroll
  for (int rr = 0; rr < 3; ++rr) {
    int s = segs[rr], e = segs[rr + 1];
    float u[8];
    #pragma unroll
    for (int k = 0; k < 8; ++k) u[k] = 0.f;

    auto accum = [&](int2 d) {
      f32x2 f;
      f = __builtin_amdgcn_cvt_pk_f32_fp8(d.x, false); u[0] += f[0]; u[1] += f[1];
      f = __builtin_amdgcn_cvt_pk_f32_fp8(d.x, true);  u[2] += f[0]; u[3] += f[1];
      f = __builtin_amdgcn_cvt_pk_f32_fp8(d.y, false); u[4] += f[0]; u[5] += f[1];
      f = __builtin_amdgcn_cvt_pk_f32_fp8(d.y, true);  u[6] += f[0]; u[7] += f[1];
    };

    int i = s;
    for (; i + 16 <= e; i += 16) {
      int t0 = ssrc[i + qt];
      int t1 = ssrc[i + 4 + qt];
      int t2 = ssrc[i + 8 + qt];
      int t3 = ssrc[i + 12 + qt];
      int2 d0 = *(const int2*)(base + (size_t)t0 * 128);
      int2 d1 = *(const int2*)(base + (size_t)t1 * 128);
      int2 d2 = *(const int2*)(base + (size_t)t2 * 128);
      int2 d3 = *(const int2*)(base + (size_t)t3 * 128);
      accum(d0); accum(d1); accum(d2); accum(d3);
    }
    for (; i + 4 <= e; i += 4) {
      int t = ssrc[i + qt];
      int2 d = *(const int2*)(base + (size_t)t * 128);
      accum(d);
    }
    if (qt < e - i) {
      int t = ssrc[i + qt];
      int2 d = *(const int2*)(base + (size_t)t * 128);
      accum(d);
    }

    #pragma unroll
    for (int k = 0; k < 8; ++k) {
      u[k] += __shfl_xor(u[k], 16);
      u[k] += __shfl_xor(u[k], 32);
    }
    if (qt == 0) {
      bf16x8 pk;
      #pragma unroll
      for (int k = 0; k < 8; ++k) pk[k] = (bf16)(u[k] * inv);
      *(bf16x8*)&lds[w][rr * 128 + ql * 8] = pk;
    }
  }

  int t = spos[node];
  if (lane < 48) {
    size_t unit = (size_t)(t >> 4) * 1024 + lane * 16 + (t & 15);
    ((bf16x8*)Aq)[unit] = *(const bf16x8*)&lds[w][lane * 8];
  }
}

// ---------------- streaming MFMA GEMM (no LDS/barriers; 4 row-blocks per wave) ----------------
struct GArgs {
  const bf16* Ap[5];
  const bf16* wf[5];
  const bf16* pf[5];
  bf16* out[5];
  const float* bias[5];
};

__global__ __launch_bounds__(256) void gemm_kernel(GArgs ga, const float4* __restrict__ cntf,
                                                   const int* __restrict__ roleinfo)
{
  const int cv = blockIdx.y;
  const bf16* __restrict__ Ap = ga.Ap[cv];
  const bf16* __restrict__ wf = ga.wf[cv];
  const bf16* __restrict__ pf = ga.pf[cv];
  bf16* __restrict__ out = ga.out[cv];
  const float* __restrict__ bias = ga.bias[cv];

  const int w = threadIdx.x >> 6, lane = threadIdx.x & 63;
  const int q = lane >> 4, l = lane & 15;
  const int rb0 = blockIdx.x * 16 + w * 4;
  const int row0 = blockIdx.x * 256;
  const int s1 = roleinfo[0], s2 = roleinfo[1];
  const int role = (row0 >= s2) ? 2 : (row0 >= s1) ? 1 : 0;
  const int laneoff = q * 128 + l;

  f32x4 acc[4][8];
  #pragma unroll
  for (int j = 0; j < 4; ++j)
    #pragma unroll
    for (int ct = 0; ct < 8; ++ct)
      #pragma unroll
      for (int k = 0; k < 4; ++k) acc[j][ct][k] = 0.f;

  const bf16x8* A0 = (const bf16x8*)Ap + (size_t)rb0 * 1024 + lane;
  const bf16x8* WF = (const bf16x8*)wf + laneoff;
  const bf16x8* PF = (const bf16x8*)pf + role * 2048 + laneoff;

  #pragma unroll 2
  for (int ks = 0; ks < 16; ++ks) {
    const bf16x8* bp = (ks < 12) ? (WF + ks * 512) : (PF + (ks - 12) * 512);
    bf16x8 a0 = A0[ks * 64];
    bf16x8 a1 = A0[1024 + ks * 64];
    bf16x8 a2 = A0[2048 + ks * 64];
    bf16x8 a3 = A0[3072 + ks * 64];
    #pragma unroll
    for (int ct = 0; ct < 8; ++ct) {
      bf16x8 b = bp[ct * 16];
      acc[0][ct] = __builtin_amdgcn_mfma_f32_16x16x32_bf16(a0, b, acc[0][ct], 0, 0, 0);
      acc[1][ct] = __builtin_amdgcn_mfma_f32_16x16x32_bf16(a1, b, acc[1][ct], 0, 0, 0);
      acc[2][ct] = __builtin_amdgcn_mfma_f32_16x16x32_bf16(a2, b, acc[2][ct], 0, 0, 0);
      acc[3][ct] = __builtin_amdgcn_mfma_f32_16x16x32_bf16(a3, b, acc[3][ct], 0, 0, 0);
    }
  }

  const bool hb = (bias != nullptr);
  #pragma unroll
  for (int j = 0; j < 4; ++j) {
    int rb = rb0 + j;
    float4 cfs[4];
    if (hb) {
      #pragma unroll
      for (int reg = 0; reg < 4; ++reg) cfs[reg] = cntf[rb * 16 + q * 4 + reg];
    }
    #pragma unroll
    for (int ct = 0; ct < 8; ++ct) {
      int col = ct * 16 + l;
      float b0 = 0, b1 = 0, b2 = 0;
      if (hb) { b0 = bias[col]; b1 = bias[128 + col]; b2 = bias[256 + col]; }
      #pragma unroll
      for (int reg = 0; reg < 4; ++reg) {
        int t = rb * 16 + q * 4 + reg;
        float v = acc[j][ct][reg];
        if (hb) v += cfs[reg].x * b0 + cfs[reg].y * b1 + cfs[reg].z * b2;
        out[(size_t)t * 128 + col] = (bf16)fmaxf(v, 0.f);
      }
    }
  }
}

// ---------------- combines ----------------
__global__ __launch_bounds__(256) void combine1_kernel(
    const bf16* __restrict__ o0, const bf16* __restrict__ o1,
    const bf16* __restrict__ o2, const bf16* __restrict__ o3,
    const float* __restrict__ h, const int* __restrict__ spos,
    float* __restrict__ zbuf, u8* __restrict__ q8, bf16* __restrict__ Aq, int N)
{
  int g = blockIdx.x * 256 + threadIdx.x;
  if (g >= N * 16) return;
  int n = g >> 4, o = g & 15;
  int t = spos[n];
  size_t tb = (size_t)t * 16 + o;
  bf16x8 a0 = ((const bf16x8*)o0)[tb];
  bf16x8 a1 = ((const bf16x8*)o1)[tb];
  bf16x8 a2 = ((const bf16x8*)o2)[tb];
  bf16x8 a3 = ((const bf16x8*)o3)[tb];
  size_t nb = (size_t)n * 16 + o;
  float4 h0 = ((const float4*)h)[nb * 2];
  float4 h1 = ((const float4*)h)[nb * 2 + 1];
  float hv[8] = {h0.x, h0.y, h0.z, h0.w, h1.x, h1.y, h1.z, h1.w};
  float zv[8], qv[8];
  bf16x8 qb;
  #pragma unroll
  for (int j = 0; j < 8; ++j) {
    zv[j] = sigmoidf_((float)a0[j] + (float)a1[j]);
    qv[j] = sigmoidf_((float)a2[j] + (float)a3[j]) * hv[j];
    qb[j] = (bf16)qv[j];
  }
  ((float4*)zbuf)[nb * 2]     = make_float4(zv[0], zv[1], zv[2], zv[3]);
  ((float4*)zbuf)[nb * 2 + 1] = make_float4(zv[4], zv[5], zv[6], zv[7]);
  int lo = __builtin_amdgcn_cvt_pk_fp8_f32(qv[0], qv[1], 0, false);
  lo = __builtin_amdgcn_cvt_pk_fp8_f32(qv[2], qv[3], lo, true);
  int hi = __builtin_amdgcn_cvt_pk_fp8_f32(qv[4], qv[5], 0, false);
  hi = __builtin_amdgcn_cvt_pk_fp8_f32(qv[6], qv[7], hi, true);
  *(int2*)(q8 + (size_t)t * 128 + o * 8) = make_int2(lo, hi);
  size_t unit = (size_t)(t >> 4) * 1024 + (48 + o) * 16 + (t & 15);
  ((bf16x8*)Aq)[unit] = qb;
}

__global__ __launch_bounds__(256) void combine2_kernel(
    const float* __restrict__ zbuf, const bf16* __restrict__ o4, const bf16* __restrict__ o5,
    const float* __restrict__ h, const int* __restrict__ spos, float* __restrict__ out, int N)
{
  int g = blockIdx.x * 256 + threadIdx.x;
  if (g >= N * 16) return;
  int n = g >> 4, o = g & 15;
  int t = spos[n];
  size_t tb = (size_t)t * 16 + o;
  bf16x8 a = ((const bf16x8*)o4)[tb];
  bf16x8 b = ((const bf16x8*)o5)[tb];
  size_t nb = (size_t)n * 16 + o;
  float4 z0 = ((const float4*)zbuf)[nb * 2];
  float4 z1 = ((const float4*)zbuf)[nb * 2 + 1];
  float4 h0 = ((const float4*)h)[nb * 2];
  float4 h1 = ((const float4*)h)[nb * 2 + 1];
  float zv[8] = {z0.x, z0.y, z0.z, z0.w, z1.x, z1.y, z1.z, z1.w};
  float hv[8] = {h0.x, h0.y, h0.z, h0.w, h1.x, h1.y, h1.z, h1.w};
  float ov[8];
  #pragma unroll
  for (int j = 0; j < 8; ++j)
    ov[j] = zv[j] * hv[j] + (1.f - zv[j]) * tanhf((float)a[j] + (float)b[j]);
  ((float4*)out)[nb * 2]     = make_float4(ov[0], ov[1], ov[2], ov[3]);
  ((float4*)out)[nb * 2 + 1] = make_float4(ov[4], ov[5], ov[6], ov[7]);
}

// ---------------- host ----------------
extern "C" void kernel_launch(void* const* d_in, const int* in_sizes, int n_in,
                              void* d_out, int out_size, void* d_ws, size_t ws_size,
                              hipStream_t stream)
{
  (void)n_in; (void)out_size; (void)ws_size;
  const float* x    = (const float*)d_in[0];
  const float* h    = (const float*)d_in[1];
  const int*   ei   = (const int*)d_in[2];
  const int*   role = (const int*)d_in[3];
  const int N = in_sizes[0] / DH;
  const int E = in_sizes[2] / 2;
  const int Etot = E + N;
  const int rows_pad = ((N + 765) + 255) & ~255;
  const int gx = rows_pad / 256;
  const int n3 = N * 3;
  const int nb3 = (n3 + 1023) / 1024;

  // conv order: 0 xz, 1 hz, 2 xr, 3 hr, 4 xh, 5 hh
  static const int Wi[6]  = {4, 9, 13, 18, 22, 27};
  static const int Wgi[6] = {5, 10, 14, 19, 23, 28};
  static const int bgi[6] = {6, 11, 15, 20, 24, 29};
  static const int Si[6]  = {7, 12, 16, 21, 25, 30};

  char* p = (char*)d_ws;
  auto alloc = [&](size_t bytes) -> char* {
    char* r = p;
    p += (bytes + 255) & ~(size_t)255;
    return r;
  };

  bf16* Ax = (bf16*)alloc((size_t)rows_pad * 512 * 2);   // Aq aliases Ax
  bf16* Ah = (bf16*)alloc((size_t)rows_pad * 512 * 2);
  bf16* Aq = Ax;
  u8* xq8  = (u8*)alloc((size_t)rows_pad * 256);
  u8* q8   = (u8*)alloc((size_t)rows_pad * 128);
  bf16* outs[6];
  for (int c = 0; c < 5; ++c) outs[c] = (bf16*)alloc((size_t)rows_pad * 128 * 2);
  outs[5] = outs[0];
  float* zbuf = (float*)alloc((size_t)N * 128 * 4);
  float4* cntf = (float4*)alloc((size_t)rows_pad * 16);
  bf16* Wf = (bf16*)alloc((size_t)6 * 49152 * 2);
  bf16* Pf = (bf16*)alloc((size_t)18 * 16384 * 2);
  int* cnt3  = (int*)alloc((size_t)n3 * 4);
  int* off3  = (int*)alloc((size_t)(n3 + 1) * 4);
  int* fill3 = (int*)alloc((size_t)n3 * 4);
  int* bsum  = (int*)alloc((size_t)(nb3 + 1) * 4);
  int* ssrc  = (int*)alloc((size_t)Etot * 4);
  int* spos  = (int*)alloc((size_t)N * 4);
  int* rolecnt  = (int*)alloc(64);
  int* rolefill = (int*)alloc(64);
  int* roleinfo = (int*)alloc(64);

  hipMemsetAsync(cnt3, 0, (size_t)n3 * 4, stream);
  hipMemsetAsync(rolecnt, 0, 16, stream);

  int egrid = (Etot + 255) / 256;
  int ngrid = (N + 255) / 256;
  hist_kernel<<<egrid, 256, 0, stream>>>(ei, role, cnt3, rolecnt, E, N);
  scan1_kernel<<<nb3, 1024, 0, stream>>>(cnt3, off3, bsum, n3);
  scan2_kernel<<<1, 64, 0, stream>>>(bsum, nb3, rolecnt, rolefill, roleinfo);
  scan3_kernel<<<nb3, 1024, 0, stream>>>(off3, fill3, bsum, n3);
  permscatter_kernel<<<ngrid, 256, 0, stream>>>(role, rolefill, spos, N);
  scatter_kernel<<<egrid, 256, 0, stream>>>(ei, spos, roleinfo, fill3, ssrc, E, N);
  zeropad_kernel<<<384, 256, 0, stream>>>(roleinfo, Ax, Ah);

  prep_xh_kernel<<<(N * 32 + 255) / 256, 256, 0, stream>>>(x, h, spos, xq8, Ax, Ah, N);

  PrepW pw;
  for (int c = 0; c < 6; ++c) {
    pw.W[c] = (const float*)d_in[Wi[c]];
    pw.Wg[c] = (const float*)d_in[Wgi[c]];
    pw.bg[c] = (const float*)d_in[bgi[c]];
  }
  prep_wf_kernel<<<1152, 256, 0, stream>>>(pw, Wf);
  PrepP pp;
  for (int c = 0; c < 6; ++c) { pp.W[c] = (const float*)d_in[Wi[c]]; pp.S[c] = (const float*)d_in[Si[c]]; }
  prep_pf_kernel<<<2304, 128, 0, stream>>>(pp, Pf);

  gather_xh_kernel<<<(N + 3) / 4, 256, 0, stream>>>(xq8, off3, ssrc, spos, Ax, Ah, cntf, N);

  // pass 1: one dispatch, cv 0..4 = {xz,xr,xh on Ax (bias)} + {hz,hr on Ah}
  GArgs g0;
  { int cvs[5] = {0, 2, 4, 1, 3};
    static const int bi2[5] = {8, 17, 26, -1, -1};
    const bf16* Apts[5] = {Ax, Ax, Ax, Ah, Ah};
    for (int k = 0; k < 5; ++k) {
      int c = cvs[k];
      g0.Ap[k] = Apts[k];
      g0.wf[k] = Wf + (size_t)c * 49152;
      g0.pf[k] = Pf + (size_t)c * 3 * 16384;
      g0.out[k] = outs[c];
      g0.bias[k] = (bi2[k] >= 0) ? (const float*)d_in[bi2[k]] : nullptr;
    } }
  gemm_kernel<<<dim3(gx, 5), 256, 0, stream>>>(g0, cntf, roleinfo);

  combine1_kernel<<<(N * 16 + 255) / 256, 256, 0, stream>>>(outs[0], outs[1], outs[2], outs[3],
                                                            h, spos, zbuf, q8, Aq, N);

  gather_q_kernel<<<(N + 3) / 4, 256, 0, stream>>>(q8, off3, ssrc, spos, Aq, N);

  // pass 2: conv hh(5) on Aq
  GArgs g2 = {};
  g2.Ap[0] = Aq;
  g2.wf[0] = Wf + (size_t)5 * 49152;
  g2.pf[0] = Pf + (size_t)5 * 3 * 16384;
  g2.out[0] = outs[5];
  g2.bias[0] = nullptr;
  gemm_kernel<<<dim3(gx, 1), 256, 0, stream>>>(g2, cntf, roleinfo);

  combine2_kernel<<<(N * 16 + 255) / 256, 256, 0, stream>>>(zbuf, outs[4], outs[5], h, spos,
                                                            (float*)d_out, N);
}